// Round 7
// baseline (1463.236 us; speedup 1.0000x reference)
//
#include <hip/hip_runtime.h>

typedef unsigned short u16;
typedef short s16x8 __attribute__((ext_vector_type(8)));
typedef float f32x4 __attribute__((ext_vector_type(4)));
typedef float f32x4u __attribute__((ext_vector_type(4), aligned(4)));
typedef unsigned short us4 __attribute__((ext_vector_type(4)));   // 8 B

__device__ __forceinline__ float bf2f(u16 v) {
    return __uint_as_float(((unsigned int)v) << 16);
}
__device__ __forceinline__ u16 f2bf(float f) {
    unsigned int u = __float_as_uint(f);
    u = u + 0x7FFFu + ((u >> 16) & 1u);
    return (u16)(u >> 16);
}
__device__ __forceinline__ f32x4 mfma16(s16x8 a, s16x8 b, f32x4 c) {
    return __builtin_amdgcn_mfma_f32_16x16x32_bf16(a, b, c, 0, 0, 0);
}
#define ZERO4 f32x4{0.f, 0.f, 0.f, 0.f}

// ---- XCD-local arrive/spin (counters zeroed by kQ each replay; never cross-XCD) ----
__device__ __forceinline__ void spin_until(unsigned* c, unsigned v) {
    if (threadIdx.x == 0) {
        while (__hip_atomic_load(c, __ATOMIC_ACQUIRE, __HIP_MEMORY_SCOPE_AGENT) != v)
            __builtin_amdgcn_s_sleep(4);
    }
    __syncthreads();
}
__device__ __forceinline__ void arrive(unsigned* c) {
    __syncthreads();                       // each wave drains vmcnt before barrier
    if (threadIdx.x == 0) {
        __threadfence();
        __hip_atomic_fetch_add(c, 1u, __ATOMIC_RELEASE, __HIP_MEMORY_SCOPE_AGENT);
    }
}

// ============ prepack: f32 weights -> bf16 MFMA B-fragment layouts ============
__global__ void prepack_kernel(const float* __restrict__ conv_w, const float* __restrict__ Wk,
                               const float* __restrict__ Wv, const float* __restrict__ Wq,
                               const float* __restrict__ W1, const float* __restrict__ W2,
                               u16* __restrict__ Bp, u16* __restrict__ WkvP, u16* __restrict__ WqP,
                               u16* __restrict__ W1T, u16* __restrict__ W2T)
{
    int idx = blockIdx.x * 256 + threadIdx.x;
    if (idx < 294912) {                       // 256 n * 1152 groups
        int n = idx / 1152, g = idx - n * 1152;
        int ic = g / 9, r = g - ic * 9;
        const float* s = conv_w + n * 3456 + ic * 27 + r * 3;
        u16* d = Bp + n * 4608 + g * 4;
        d[0] = f2bf(s[0]); d[1] = f2bf(s[1]); d[2] = f2bf(s[2]); d[3] = 0;
    } else if (idx < 425984) {                // WkvP 512*256
        int i = idx - 294912;
        int n = i >> 8, c = i & 255;
        WkvP[i] = f2bf((n < 256) ? Wk[c * 256 + n] : Wv[c * 256 + (n - 256)]);
    } else if (idx < 491520) {                // WqP 256*256
        int i = idx - 425984;
        int n = i >> 8, c = i & 255;
        WqP[i] = f2bf(Wq[c * 256 + n]);
    } else if (idx < 622592) {                // W1T 512*256
        int i = idx - 491520;
        int h = i >> 8, c = i & 255;
        W1T[i] = f2bf(W1[c * 512 + h]);
    } else if (idx < 753664) {                // W2T 256*512
        int i = idx - 622592;
        int dd = i >> 9, h = i & 511;
        W2T[i] = f2bf(W2[h * 256 + dd]);
    }
}

// ============ fused conv3d(s2)+bias+ReLU+LN_in + k/v GEMM (unchanged from R6) ============
__global__ __launch_bounds__(512, 4) void conv_fused(
    const float* __restrict__ x, const u16* __restrict__ Bp, const float* __restrict__ conv_b,
    const float* __restrict__ ln_g, const float* __restrict__ ln_b, const u16* __restrict__ WkvP,
    u16* __restrict__ kbuf, u16* __restrict__ vT)
{
    __shared__ __align__(16) char smem[66816];
    u16* slab0  = (u16*)smem;                 // [432 rows][36 iz] u16 = 31104 B
    u16* slab1  = (u16*)(smem + 31104);       // second buffer
    u16* tokbf  = (u16*)smem;                 // alias after conv: [64 m][264 c] = 33792 B
    float* lnred  = (float*)(smem + 62208);   // [8 w][64 m][2] = 4096
    float* lnstat = (float*)(smem + 66304);   // [64 m][2] = 512

    int blk = blockIdx.x;
    int b = blk & 7, ox = (blk >> 5) & 15, oyb = (blk >> 3) & 3;   // XCD pin: b = blk%8
    int tid = threadIdx.x, wid = tid >> 6, lane = tid & 63;
    int quad = lane >> 4, l15 = lane & 15;
    int nbase = wid * 32;                     // conv n-slice: 32 channels/wave

    f32x4 acc[4][2];
    #pragma unroll
    for (int i = 0; i < 4; ++i)
        #pragma unroll
        for (int j = 0; j < 2; ++j) acc[i][j] = ZERO4;

    const u16* bprow0 = Bp + (nbase + l15) * 4608 + quad * 8;
    const u16* bprow1 = bprow0 + 16 * 4608;

    const float* xp[8]; int so8[8]; unsigned wmask = 0;
    #pragma unroll
    for (int u = 0; u < 8; ++u) {
        int s = tid + u * 512;
        so8[u] = -1; xp[u] = x;
        if (s < 3888) {
            int row = s / 9;
            int c = s - row * 9;
            int icl = row / 27;
            int rr = row - icl * 27;
            int ixl = rr / 9;
            int iyl = rr - ixl * 9;
            const float* xr = x + ((size_t)((b * 128 + icl) * 33) + (2 * ox + ixl)) * 1089
                              + (8 * oyb + iyl) * 33;
            if (c < 8) { xp[u] = xr + c * 4; wmask |= (1u << u); }
            else       { xp[u] = xr + 32; }
            so8[u] = row * 36 + c * 4;
        }
    }
    const size_t ICST = 16ull * 35937;

    f32x4u tv[8];
#define LOADX(ICC)                                                          \
    {                                                                       \
        _Pragma("unroll")                                                   \
        for (int u = 0; u < 8; ++u) {                                       \
            if (so8[u] >= 0) {                                              \
                const float* p = xp[u] + (size_t)(ICC) * ICST;              \
                if ((wmask >> u) & 1u) tv[u] = *(const f32x4u*)p;           \
                else                   tv[u] = f32x4u{p[0], 0.f, 0.f, 0.f}; \
            }                                                               \
        }                                                                   \
    }
#define STOREX(DST)                                                         \
    {                                                                       \
        _Pragma("unroll")                                                   \
        for (int u = 0; u < 8; ++u) {                                       \
            if (so8[u] >= 0) {                                              \
                us4 w;                                                      \
                w.x = f2bf(tv[u].x); w.y = f2bf(tv[u].y);                   \
                w.z = f2bf(tv[u].z); w.w = f2bf(tv[u].w);                   \
                *(us4*)((DST) + so8[u]) = w;                                \
            }                                                               \
        }                                                                   \
    }

    LOADX(0)
    STOREX(slab0)
    __syncthreads();

    for (int icc = 0; icc < 8; ++icc) {
        const u16* cur = (icc & 1) ? slab1 : slab0;
        u16* nxt = (icc & 1) ? slab0 : slab1;
        if (icc < 7) LOADX(icc + 1)

        const u16* bk0 = bprow0 + icc * 576;
        const u16* bk1 = bprow1 + icc * 576;
        s16x8 bbA[2], bbB[2];
        bbA[0] = *reinterpret_cast<const s16x8*>(bk0);
        bbA[1] = *reinterpret_cast<const s16x8*>(bk1);

#define CONV_STEP(CC, BREG)                                                     \
        {                                                                       \
            int g = (CC) * 8 + quad * 2;                                        \
            int i0 = g / 9, r9 = g - i0 * 9;                                    \
            int kx = r9 / 3, ky = r9 - kx * 3;                                  \
            int base0 = (i0 * 27 + kx * 9 + ky) * 36 + 2 * l15;                 \
            g += 1;                                                             \
            i0 = g / 9; r9 = g - i0 * 9; kx = r9 / 3; ky = r9 - kx * 3;         \
            int base1 = (i0 * 27 + kx * 9 + ky) * 36 + 2 * l15;                 \
            _Pragma("unroll")                                                   \
            for (int fm = 0; fm < 4; ++fm) {                                    \
                union { s16x8 v; ushort2 h[4]; } af;                            \
                const u16* sp0 = cur + base0 + fm * 72;                         \
                const u16* sp1 = cur + base1 + fm * 72;                         \
                af.h[0] = *(const ushort2*)(sp0);                               \
                af.h[1] = *(const ushort2*)(sp0 + 2);                           \
                af.h[2] = *(const ushort2*)(sp1);                               \
                af.h[3] = *(const ushort2*)(sp1 + 2);                           \
                acc[fm][0] = mfma16(af.v, (BREG)[0], acc[fm][0]);               \
                acc[fm][1] = mfma16(af.v, (BREG)[1], acc[fm][1]);               \
            }                                                                   \
        }

        #pragma unroll 1
        for (int c8 = 0; c8 < 18; c8 += 2) {
            bbB[0] = *reinterpret_cast<const s16x8*>(bk0 + (c8 + 1) * 32);
            bbB[1] = *reinterpret_cast<const s16x8*>(bk1 + (c8 + 1) * 32);
            CONV_STEP(c8, bbA)
            if (c8 + 2 < 18) {
                bbA[0] = *reinterpret_cast<const s16x8*>(bk0 + (c8 + 2) * 32);
                bbA[1] = *reinterpret_cast<const s16x8*>(bk1 + (c8 + 2) * 32);
            }
            CONV_STEP(c8 + 1, bbB)
        }
#undef CONV_STEP
        if (icc < 7) STOREX(nxt)
        __syncthreads();
    }
#undef LOADX
#undef STOREX

    #pragma unroll
    for (int fn = 0; fn < 2; ++fn) {
        float bias = conv_b[nbase + fn * 16 + l15];
        #pragma unroll
        for (int fm = 0; fm < 4; ++fm)
            #pragma unroll
            for (int r = 0; r < 4; ++r)
                acc[fm][fn][r] = fmaxf(acc[fm][fn][r] + bias, 0.f);
    }
    #pragma unroll
    for (int fm = 0; fm < 4; ++fm) {
        #pragma unroll
        for (int r = 0; r < 4; ++r) {
            float s = acc[fm][0][r] + acc[fm][1][r];
            float q2 = acc[fm][0][r] * acc[fm][0][r] + acc[fm][1][r] * acc[fm][1][r];
            #pragma unroll
            for (int msk = 1; msk <= 8; msk <<= 1) {
                s  += __shfl_xor(s, msk, 64);
                q2 += __shfl_xor(q2, msk, 64);
            }
            if (l15 == 0) {
                int mm = fm * 16 + quad * 4 + r;
                lnred[(wid * 64 + mm) * 2 + 0] = s;
                lnred[(wid * 64 + mm) * 2 + 1] = q2;
            }
        }
    }
    __syncthreads();
    if (tid < 64) {
        float s = 0, q2 = 0;
        #pragma unroll
        for (int w = 0; w < 8; ++w) { s += lnred[(w * 64 + tid) * 2]; q2 += lnred[(w * 64 + tid) * 2 + 1]; }
        float mu = s * (1.f / 256.f);
        float var = fmaxf(q2 * (1.f / 256.f) - mu * mu, 0.f);
        lnstat[tid * 2]     = mu;
        lnstat[tid * 2 + 1] = rsqrtf(var + 1e-5f);
    }
    __syncthreads();
    {
        float gam[2], bet[2];
        #pragma unroll
        for (int fn = 0; fn < 2; ++fn) {
            int n = nbase + fn * 16 + l15;
            gam[fn] = ln_g[n]; bet[fn] = ln_b[n];
        }
        #pragma unroll
        for (int fm = 0; fm < 4; ++fm)
            #pragma unroll
            for (int r = 0; r < 4; ++r) {
                int mm = fm * 16 + quad * 4 + r;
                float mu = lnstat[mm * 2], rs = lnstat[mm * 2 + 1];
                #pragma unroll
                for (int fn = 0; fn < 2; ++fn) {
                    int n = nbase + fn * 16 + l15;
                    tokbf[mm * 264 + n] = f2bf((acc[fm][fn][r] - mu) * rs * gam[fn] + bet[fn]);
                }
            }
    }
    __syncthreads();
    f32x4 kacc[4][4];
    #pragma unroll
    for (int i = 0; i < 4; ++i)
        #pragma unroll
        for (int j = 0; j < 4; ++j) kacc[i][j] = ZERO4;
    int n2 = wid * 64;
    const u16* wp = WkvP + (n2 + l15) * 256 + quad * 8;
    s16x8 wvA[4], wvB[4];
    #pragma unroll
    for (int fn = 0; fn < 4; ++fn) wvA[fn] = *reinterpret_cast<const s16x8*>(wp + fn * 4096);

#define KV_STEP(KK, WREG)                                                           \
    {                                                                               \
        s16x8 a2[4];                                                                \
        _Pragma("unroll")                                                           \
        for (int fm = 0; fm < 4; ++fm)                                              \
            a2[fm] = *reinterpret_cast<const s16x8*>(tokbf + (fm * 16 + l15) * 264  \
                                                     + (KK) * 32 + quad * 8);       \
        _Pragma("unroll")                                                           \
        for (int fn = 0; fn < 4; ++fn)                                              \
            _Pragma("unroll")                                                       \
            for (int fm = 0; fm < 4; ++fm)                                          \
                kacc[fm][fn] = mfma16(a2[fm], (WREG)[fn], kacc[fm][fn]);            \
    }

    #pragma unroll 1
    for (int kc = 0; kc < 8; kc += 2) {
        #pragma unroll
        for (int fn = 0; fn < 4; ++fn)
            wvB[fn] = *reinterpret_cast<const s16x8*>(wp + fn * 4096 + (kc + 1) * 32);
        KV_STEP(kc, wvA)
        if (kc + 2 < 8) {
            #pragma unroll
            for (int fn = 0; fn < 4; ++fn)
                wvA[fn] = *reinterpret_cast<const s16x8*>(wp + fn * 4096 + (kc + 2) * 32);
        }
        KV_STEP(kc + 1, wvB)
    }
#undef KV_STEP

    #pragma unroll
    for (int fm = 0; fm < 4; ++fm)
        #pragma unroll
        for (int r = 0; r < 4; ++r) {
            int l = (ox * 16 + oyb * 4 + fm) * 16 + quad * 4 + r;
            #pragma unroll
            for (int fn = 0; fn < 4; ++fn) {
                int n = n2 + fn * 16 + l15;
                u16 v = f2bf(kacc[fm][fn][r]);
                if (n < 256) kbuf[((b << 12) + l) * 256 + n] = v;           // k[b][l][d]
                else         vT[((b * 256 + (n - 256)) << 12) + l] = v;     // vT[b][d][l]
            }
        }
}

// ============ kQ: init tpl; LN_t + q (iter 0); zero delta + sync counters ============
__global__ __launch_bounds__(256) void kQ(
    const float* __restrict__ tinit, float* __restrict__ tpl,
    const float* __restrict__ ln_t_g, const float* __restrict__ ln_t_b,
    const u16* __restrict__ WqP, u16* __restrict__ qbuf, float* __restrict__ delta,
    unsigned* __restrict__ cnts)
{
    __shared__ __align__(16) u16 mls[64 * 264];
    __shared__ float pls[64][4][2];
    __shared__ float stat[64][2];
    int b = blockIdx.x, tid = threadIdx.x;
    if (b == 0 && tid < 96) cnts[tid] = 0;    // cnt[8][6] + qrdy[8][6]
    int m = tid >> 2, part = tid & 3;
    const float* tp = tinit + m * 256 + part * 64;
    float* tg = tpl + (b * 64 + m) * 256 + part * 64;
    float s = 0, q2 = 0;
    for (int i = 0; i < 64; ++i) {
        float v = tp[i];
        tg[i] = v;
        s += v; q2 += v * v;
    }
    pls[m][part][0] = s; pls[m][part][1] = q2;
    __syncthreads();
    if (tid < 64) {
        float ss = 0, qq = 0;
        #pragma unroll
        for (int p = 0; p < 4; ++p) { ss += pls[tid][p][0]; qq += pls[tid][p][1]; }
        float mu = ss * (1.f / 256.f);
        float var = fmaxf(qq * (1.f / 256.f) - mu * mu, 0.f);
        stat[tid][0] = mu; stat[tid][1] = rsqrtf(var + 1e-5f);
    }
    __syncthreads();
    {
        float mu = stat[m][0], rs = stat[m][1];
        for (int i = 0; i < 64; ++i) {
            int d = part * 64 + i;
            mls[m * 264 + d] = f2bf((tp[i] - mu) * rs * ln_t_g[d] + ln_t_b[d]);
        }
    }
    __syncthreads();
    int wid = tid >> 6, lane = tid & 63, quad = lane >> 4, l15 = lane & 15;
    f32x4 qa[4][4];
    #pragma unroll
    for (int i = 0; i < 4; ++i)
        #pragma unroll
        for (int j = 0; j < 4; ++j) qa[i][j] = ZERO4;
    #pragma unroll 1
    for (int kc = 0; kc < 8; ++kc) {
        s16x8 a[4];
        #pragma unroll
        for (int fm = 0; fm < 4; ++fm)
            a[fm] = *reinterpret_cast<const s16x8*>(mls + (fm * 16 + l15) * 264 + kc * 32 + quad * 8);
        #pragma unroll
        for (int fn = 0; fn < 4; ++fn) {
            s16x8 bv = *reinterpret_cast<const s16x8*>(WqP + (wid * 64 + fn * 16 + l15) * 256 + kc * 32 + quad * 8);
            #pragma unroll
            for (int fm = 0; fm < 4; ++fm)
                qa[fm][fn] = mfma16(a[fm], bv, qa[fm][fn]);
        }
    }
    #pragma unroll
    for (int fm = 0; fm < 4; ++fm)
        #pragma unroll
        for (int fn = 0; fn < 4; ++fn)
            #pragma unroll
            for (int r = 0; r < 4; ++r) {
                int mt = fm * 16 + quad * 4 + r;
                int d = wid * 64 + fn * 16 + l15;
                qbuf[(b * 64 + mt) * 256 + d] = f2bf(qa[fm][fn][r] * 0.0625f);
            }
    f32x4* dz = (f32x4*)(delta + b * 16384);
    for (int i = tid; i < 4096; i += 256) dz[i] = ZERO4;
}

// ============ kMega: ALL 6 iterations in one launch; XCD-local producer/consumer sync ======
// grid 256 (1 block/CU, all co-resident); b = blk&7 so batch b's 32 blocks share XCD b.
// Per iter: all 32 blocks do QK^T+softmax+PV-atomics, arrive(cnt). 4 consumer blocks
// (ltg<4) spin cnt==32, run template update (kT) + q for next iter, zero their delta
// slice, arrive(qrdy). Next iter gates on qrdy==4. No device-wide sync anywhere.
__global__ __launch_bounds__(512, 2) void kMega(
    u16* __restrict__ qbuf, const u16* __restrict__ kbuf, const u16* __restrict__ vT,
    float* __restrict__ cs_part, float* __restrict__ delta, u16* __restrict__ attnT,
    float* __restrict__ tpl,
    const float* __restrict__ ln_m_g, const float* __restrict__ ln_m_b,
    const u16* __restrict__ W1T, const float* __restrict__ b1,
    const u16* __restrict__ W2T, const float* __restrict__ b2,
    const float* __restrict__ ln_t_g, const float* __restrict__ ln_t_b,
    const u16* __restrict__ WqP,
    unsigned* __restrict__ cnt, unsigned* __restrict__ qrdy,
    float* __restrict__ out0, float* __restrict__ out1)
{
    __shared__ __align__(16) char smem[53248];
    u16* qls     = (u16*)smem;                  // [64][264] = 33792 (phase A)
    u16* atile   = (u16*)(smem + 33792);        // [64][136] = 17408
    float* colsh = (float*)(smem + 51200);      // [8][64]   = 2048
    // kT-phase aliases (inside qls region; qls dead after phase A of each iter)
    u16* mls    = (u16*)smem;                   // [16][264] = 8448
    u16* hid    = (u16*)(smem + 8448);          // [16][520] = 16640
    float* pls  = (float*)(smem + 25088);       // [16][32][2] = 4096
    float* stat = (float*)(smem + 29184);       // [16][2] = 128
    float* lnr2 = (float*)(smem + 29312);       // [8][16][2] = 1024
    float* csh  = (float*)(smem + 30336);       // [16] = 64

    int b = blockIdx.x & 7, ltg = blockIdx.x >> 3;    // XCD pin
    int tid = threadIdx.x, wid = tid >> 6, lane = tid & 63;
    int quad = lane >> 4, l15 = lane & 15;

    // k-row fragments are loop-invariant: load ONCE for all 6 iterations
    int lrow = ltg * 128 + wid * 16;
    const u16* arow = kbuf + (size_t)((b << 12) + lrow + l15) * 256;
    s16x8 av[8];
    #pragma unroll
    for (int kc = 0; kc < 8; ++kc)
        av[kc] = *reinterpret_cast<const s16x8*>(arow + kc * 32 + quad * 8);
    const u16* vrow = vT + ((size_t)(b * 256 + wid * 32 + l15) << 12) + ltg * 128 + quad * 8;

    #pragma unroll 1
    for (int it = 0; it < 6; ++it) {
        int last = (it == 5);
        if (it > 0) spin_until(&qrdy[b * 6 + it - 1], 4u);
        // ---- stage q[b] into LDS ----
        {
            int r = tid >> 3, c = (tid & 7) * 32;
            const u16* src = qbuf + b * 16384 + r * 256 + c;
            u16* dst = qls + r * 264 + c;
            #pragma unroll
            for (int j = 0; j < 4; ++j)
                *(int4*)(dst + j * 8) = *(const int4*)(src + j * 8);
        }
        // ---- vT loads issued now; latency hidden under staging + phase A ----
        s16x8 bv2[2][4];
        #pragma unroll
        for (int fn = 0; fn < 2; ++fn)
            #pragma unroll
            for (int kc = 0; kc < 4; ++kc)
                bv2[fn][kc] = *reinterpret_cast<const s16x8*>(vrow + (fn << 16) + kc * 32);
        __syncthreads();
        // ---- Phase A: QK^T + softmax(N) ----
        f32x4 sa[4];
        #pragma unroll
        for (int fn = 0; fn < 4; ++fn) sa[fn] = ZERO4;
        #pragma unroll
        for (int kc = 0; kc < 8; ++kc) {
            #pragma unroll
            for (int fn = 0; fn < 4; ++fn) {
                s16x8 bv = *reinterpret_cast<const s16x8*>(qls + (fn * 16 + l15) * 264 + kc * 32 + quad * 8);
                sa[fn] = mfma16(av[kc], bv, sa[fn]);
            }
        }
        float colp[4] = {0.f, 0.f, 0.f, 0.f};
        #pragma unroll
        for (int r = 0; r < 4; ++r) {
            float mx = fmaxf(fmaxf(sa[0][r], sa[1][r]), fmaxf(sa[2][r], sa[3][r]));
            #pragma unroll
            for (int msk = 1; msk <= 8; msk <<= 1) mx = fmaxf(mx, __shfl_xor(mx, msk, 64));
            float e[4], sum = 0;
            #pragma unroll
            for (int fn = 0; fn < 4; ++fn) { e[fn] = __expf(sa[fn][r] - mx); sum += e[fn]; }
            #pragma unroll
            for (int msk = 1; msk <= 8; msk <<= 1) sum += __shfl_xor(sum, msk, 64);
            float inv = 1.f / sum;
            #pragma unroll
            for (int fn = 0; fn < 4; ++fn) {
                float p = e[fn] * inv + 1e-8f;
                colp[fn] += p;
                atile[(fn * 16 + l15) * 136 + wid * 16 + quad * 4 + r] = f2bf(p);
            }
        }
        #pragma unroll
        for (int fn = 0; fn < 4; ++fn) {
            float c = colp[fn];
            c += __shfl_xor(c, 16, 64);
            c += __shfl_xor(c, 32, 64);
            if (lane < 16) colsh[wid * 64 + fn * 16 + lane] = c;
        }
        __syncthreads();
        if (tid < 64) {
            float s = 0;
            #pragma unroll
            for (int w = 0; w < 8; ++w) s += colsh[w * 64 + tid];
            cs_part[((b << 5) + ltg) * 64 + tid] = s;
        }
        // ---- Phase B: PV (K = this block's 128 l) -> delta atomics ----
        {
            f32x4 pacc[4][2];
            #pragma unroll
            for (int i = 0; i < 4; ++i)
                #pragma unroll
                for (int j = 0; j < 2; ++j) pacc[i][j] = ZERO4;
            #pragma unroll
            for (int kc = 0; kc < 4; ++kc) {
                #pragma unroll
                for (int fm = 0; fm < 4; ++fm) {
                    s16x8 a = *reinterpret_cast<const s16x8*>(atile + (fm * 16 + l15) * 136 + kc * 32 + quad * 8);
                    #pragma unroll
                    for (int fn = 0; fn < 2; ++fn)
                        pacc[fm][fn] = mfma16(a, bv2[fn][kc], pacc[fm][fn]);
                }
            }
            #pragma unroll
            for (int fm = 0; fm < 4; ++fm)
                #pragma unroll
                for (int fn = 0; fn < 2; ++fn)
                    #pragma unroll
                    for (int r = 0; r < 4; ++r) {
                        int n = fm * 16 + quad * 4 + r;
                        int d = wid * 32 + fn * 16 + l15;
                        atomicAdd(&delta[(size_t)(b * 64 + n) * 256 + d], pacc[fm][fn][r]);
                    }
        }
        // ---- Phase C: P -> attnT on last iter ----
        if (last) {
            int n = tid >> 3, lo = (tid & 7) * 16;
            const u16* src = atile + n * 136 + lo;
            u16* dst = attnT + (size_t)((b * 64 + n) << 12) + ltg * 128 + lo;
            *(int4*)(dst)     = *(const int4*)(src);
            *(int4*)(dst + 8) = *(const int4*)(src + 8);
        }
        arrive(&cnt[b * 6 + it]);

        // ---------- consumer blocks: template update ----------
        if (ltg < 4) {
            spin_until(&cnt[b * 6 + it], 32u);
            int m0 = ltg * 16;
            if (tid < 16) {
                float s = 0;
                #pragma unroll
                for (int g = 0; g < 32; ++g) s += cs_part[((b << 5) + g) * 64 + m0 + tid];
                csh[tid] = 1.f / s;
            }
            __syncthreads();
            // phase 1: v = tpl + delta/colsum; zero delta slice; LN_m -> mls; tpl = v
            {
                int ml = tid >> 5, part = tid & 31;
                float cinv = csh[ml];
                float* tg = tpl + (b * 64 + m0 + ml) * 256 + part * 8;
                float* dg = delta + (size_t)(b * 64 + m0 + ml) * 256 + part * 8;
                float vbuf[8];
                float s = 0, q2 = 0;
                #pragma unroll
                for (int i = 0; i < 8; ++i) {
                    float v = tg[i] + dg[i] * cinv;
                    vbuf[i] = v; s += v; q2 += v * v;
                }
                if (!last) {
                    f32x4* dz = (f32x4*)dg;
                    dz[0] = ZERO4; dz[1] = ZERO4;
                }
                pls[(ml * 32 + part) * 2 + 0] = s; pls[(ml * 32 + part) * 2 + 1] = q2;
                __syncthreads();
                if (tid < 16) {
                    float ss = 0, qq = 0;
                    #pragma unroll
                    for (int p = 0; p < 32; ++p) { ss += pls[(tid * 32 + p) * 2]; qq += pls[(tid * 32 + p) * 2 + 1]; }
                    float mu = ss * (1.f / 256.f);
                    float var = fmaxf(qq * (1.f / 256.f) - mu * mu, 0.f);
                    stat[tid * 2] = mu; stat[tid * 2 + 1] = rsqrtf(var + 1e-5f);
                }
                __syncthreads();
                float mu = stat[ml * 2], rs = stat[ml * 2 + 1];
                #pragma unroll
                for (int i = 0; i < 8; ++i) {
                    int d = part * 8 + i;
                    tg[i] = vbuf[i];
                    mls[ml * 264 + d] = f2bf((vbuf[i] - mu) * rs * ln_m_g[d] + ln_m_b[d]);
                }
            }
            __syncthreads();
            // G1: hid = gelu(mls @ W1 + b1); 8 waves, wave -> 64 nh
            {
                f32x4 ha[4];
                #pragma unroll
                for (int j = 0; j < 4; ++j) ha[j] = ZERO4;
                #pragma unroll 1
                for (int kc = 0; kc < 8; ++kc) {
                    s16x8 a = *reinterpret_cast<const s16x8*>(mls + l15 * 264 + kc * 32 + quad * 8);
                    #pragma unroll
                    for (int fn = 0; fn < 4; ++fn) {
                        s16x8 bv = *reinterpret_cast<const s16x8*>(W1T + (wid * 64 + fn * 16 + l15) * 256 + kc * 32 + quad * 8);
                        ha[fn] = mfma16(a, bv, ha[fn]);
                    }
                }
                #pragma unroll
                for (int fn = 0; fn < 4; ++fn) {
                    int nh = wid * 64 + fn * 16 + l15;
                    float bb = b1[nh];
                    #pragma unroll
                    for (int r = 0; r < 4; ++r) {
                        float v = ha[fn][r] + bb;
                        v = 0.5f * v * (1.f + erff(v * 0.70710678118654752f));
                        hid[(quad * 4 + r) * 520 + nh] = f2bf(v);
                    }
                }
            }
            __syncthreads();
            // G2: new = tpl + hid @ W2 + b2; LN_t -> mls; out0 on last; wave -> 32 d
            {
                f32x4 oa[2];
                oa[0] = ZERO4; oa[1] = ZERO4;
                #pragma unroll 1
                for (int kc = 0; kc < 16; ++kc) {
                    s16x8 a = *reinterpret_cast<const s16x8*>(hid + l15 * 520 + kc * 32 + quad * 8);
                    #pragma unroll
                    for (int fn = 0; fn < 2; ++fn) {
                        s16x8 bv = *reinterpret_cast<const s16x8*>(W2T + (wid * 32 + fn * 16 + l15) * 512 + kc * 32 + quad * 8);
                        oa[fn] = mfma16(a, bv, oa[fn]);
                    }
                }
                #pragma unroll
                for (int fn = 0; fn < 2; ++fn) {
                    int d = wid * 32 + fn * 16 + l15;
                    float bb = b2[d];
                    #pragma unroll
                    for (int r = 0; r < 4; ++r) {
                        int mm = quad * 4 + r;
                        oa[fn][r] += bb + tpl[(b * 64 + m0 + mm) * 256 + d];
                    }
                }
                #pragma unroll
                for (int r = 0; r < 4; ++r) {
                    float s = oa[0][r] + oa[1][r];
                    float q2 = oa[0][r] * oa[0][r] + oa[1][r] * oa[1][r];
                    #pragma unroll
                    for (int msk = 1; msk <= 8; msk <<= 1) {
                        s  += __shfl_xor(s, msk, 64);
                        q2 += __shfl_xor(q2, msk, 64);
                    }
                    if (l15 == 0) {
                        lnr2[(wid * 16 + quad * 4 + r) * 2 + 0] = s;
                        lnr2[(wid * 16 + quad * 4 + r) * 2 + 1] = q2;
                    }
                }
                __syncthreads();
                if (tid < 16) {
                    float ss = 0, qq = 0;
                    #pragma unroll
                    for (int w = 0; w < 8; ++w) { ss += lnr2[(w * 16 + tid) * 2]; qq += lnr2[(w * 16 + tid) * 2 + 1]; }
                    float mu = ss * (1.f / 256.f);
                    float var = fmaxf(qq * (1.f / 256.f) - mu * mu, 0.f);
                    stat[tid * 2] = mu; stat[tid * 2 + 1] = rsqrtf(var + 1e-5f);
                }
                __syncthreads();
                #pragma unroll
                for (int fn = 0; fn < 2; ++fn) {
                    int d = wid * 32 + fn * 16 + l15;
                    float gg = last ? 0.f : ln_t_g[d];
                    float bt = last ? 0.f : ln_t_b[d];
                    #pragma unroll
                    for (int r = 0; r < 4; ++r) {
                        int mm = quad * 4 + r;
                        float v = oa[fn][r];
                        tpl[(b * 64 + m0 + mm) * 256 + d] = v;
                        if (last) {
                            out0[(b * 256 + d) * 64 + m0 + mm] = v;
                        } else {
                            mls[mm * 264 + d] = f2bf((v - stat[mm * 2]) * stat[mm * 2 + 1] * gg + bt);
                        }
                    }
                }
            }
            if (!last) {
                __syncthreads();
                // q-GEMM for next iteration; wave -> 32 d
                f32x4 qa[2];
                qa[0] = ZERO4; qa[1] = ZERO4;
                #pragma unroll 1
                for (int kc = 0; kc < 8; ++kc) {
                    s16x8 a = *reinterpret_cast<const s16x8*>(mls + l15 * 264 + kc * 32 + quad * 8);
                    #pragma unroll
                    for (int fn = 0; fn < 2; ++fn) {
                        s16x8 bv = *reinterpret_cast<const s16x8*>(WqP + (wid * 32 + fn * 16 + l15) * 256 + kc * 32 + quad * 8);
                        qa[fn] = mfma16(a, bv, qa[fn]);
                    }
                }
                #pragma unroll
                for (int fn = 0; fn < 2; ++fn)
                    #pragma unroll
                    for (int r = 0; r < 4; ++r) {
                        int mt = m0 + quad * 4 + r;
                        int d = wid * 32 + fn * 16 + l15;
                        qbuf[(b * 64 + mt) * 256 + d] = f2bf(qa[fn][r] * 0.0625f);
                    }
                arrive(&qrdy[b * 6 + it]);
            } else {
                // kE: attn_out = attnT / colsum for this block's 16 n rows
                __syncthreads();
                int n = m0 + (tid >> 5);
                int c0 = (tid & 31) * 128;
                float ci = csh[tid >> 5];
                const u16* src = attnT + ((size_t)(b * 64 + n) << 12) + c0;
                float* dst = out1 + ((size_t)(b * 64 + n) << 12) + c0;
                #pragma unroll
                for (int j = 0; j < 128; j += 4) {
                    us4 w = *(const us4*)(src + j);
                    f32x4 o;
                    o.x = bf2f(w.x) * ci; o.y = bf2f(w.y) * ci;
                    o.z = bf2f(w.z) * ci; o.w = bf2f(w.w) * ci;
                    *(f32x4*)(dst + j) = o;
                }
            }
        }
    }
}

// ============ launch ============
extern "C" void kernel_launch(void* const* d_in, const int* in_sizes, int n_in,
                              void* d_out, int out_size, void* d_ws, size_t ws_size,
                              hipStream_t stream)
{
    const float* x       = (const float*)d_in[0];
    const float* tinit   = (const float*)d_in[1];
    const float* conv_w  = (const float*)d_in[2];
    const float* conv_b  = (const float*)d_in[3];
    const float* Wq      = (const float*)d_in[4];
    const float* Wk      = (const float*)d_in[5];
    const float* Wv      = (const float*)d_in[6];
    const float* ln_in_g = (const float*)d_in[7];
    const float* ln_in_b = (const float*)d_in[8];
    const float* ln_t_g  = (const float*)d_in[9];
    const float* ln_t_b  = (const float*)d_in[10];
    const float* ln_m_g  = (const float*)d_in[11];
    const float* ln_m_b  = (const float*)d_in[12];
    const float* W1      = (const float*)d_in[13];
    const float* b1      = (const float*)d_in[14];
    const float* W2      = (const float*)d_in[15];
    const float* b2      = (const float*)d_in[16];

    char* ws = (char*)d_ws;
    u16* Bp       = (u16*)(ws + 0);          // 2,359,296
    u16* WkvP     = (u16*)(ws + 2359296);    //   262,144
    u16* WqP      = (u16*)(ws + 2621440);    //   131,072
    u16* W1T      = (u16*)(ws + 2752512);    //   262,144
    u16* W2T      = (u16*)(ws + 3014656);    //   262,144
    u16* kbuf     = (u16*)(ws + 3276800);    // 16,777,216
    u16* vT       = (u16*)(ws + 20054016);   // 16,777,216
    u16* qbuf     = (u16*)(ws + 36831232);   //   262,144
    u16* attnT    = (u16*)(ws + 37093376);   // 4,194,304  (written last iter only)
    unsigned* cnts= (unsigned*)(ws + 41287680); //  384 B  (cnt[48] + qrdy[48])
    float* tpl    = (float*)(ws + 41289728); //   524,288
    float* delta  = (float*)(ws + 41814016); //   524,288
    float* cs_part= (float*)(ws + 42338304); //    65,536   (total ~42.4 MB)

    float* out0 = (float*)d_out;      // templates_out (8,256,64)
    float* out1 = out0 + 131072;      // attn_out (8,64,16,16,16)

    unsigned* cnt  = cnts;
    unsigned* qrdy = cnts + 48;

    prepack_kernel<<<2944, 256, 0, stream>>>(conv_w, Wk, Wv, Wq, W1, W2, Bp, WkvP, WqP, W1T, W2T);
    conv_fused<<<512, 512, 0, stream>>>(x, Bp, conv_b, ln_in_g, ln_in_b, WkvP, kbuf, vT);
    kQ<<<8, 256, 0, stream>>>(tinit, tpl, ln_t_g, ln_t_b, WqP, qbuf, delta, cnts);
    kMega<<<256, 512, 0, stream>>>(qbuf, kbuf, vT, cs_part, delta, attnT, tpl,
                                   ln_m_g, ln_m_b, W1T, b1, W2T, b2,
                                   ln_t_g, ln_t_b, WqP, cnt, qrdy, out0, out1);
}

// Round 8
// 798.160 us; speedup vs baseline: 1.8333x; 1.8333x over previous
//
#include <hip/hip_runtime.h>

typedef unsigned short u16;
typedef short s16x8 __attribute__((ext_vector_type(8)));
typedef float f32x4 __attribute__((ext_vector_type(4)));
typedef float f32x4u __attribute__((ext_vector_type(4), aligned(4)));
typedef unsigned short us4 __attribute__((ext_vector_type(4)));   // 8 B

__device__ __forceinline__ float bf2f(u16 v) {
    return __uint_as_float(((unsigned int)v) << 16);
}
__device__ __forceinline__ u16 f2bf(float f) {
    unsigned int u = __float_as_uint(f);
    u = u + 0x7FFFu + ((u >> 16) & 1u);
    return (u16)(u >> 16);
}
__device__ __forceinline__ f32x4 mfma16(s16x8 a, s16x8 b, f32x4 c) {
    return __builtin_amdgcn_mfma_f32_16x16x32_bf16(a, b, c, 0, 0, 0);
}
#define ZERO4 f32x4{0.f, 0.f, 0.f, 0.f}

// ============ prepack: f32 weights -> bf16 MFMA B-fragment layouts ============
__global__ void prepack_kernel(const float* __restrict__ conv_w, const float* __restrict__ Wk,
                               const float* __restrict__ Wv, const float* __restrict__ Wq,
                               const float* __restrict__ W1, const float* __restrict__ W2,
                               u16* __restrict__ Bp, u16* __restrict__ WkvP, u16* __restrict__ WqP,
                               u16* __restrict__ W1T, u16* __restrict__ W2T)
{
    int idx = blockIdx.x * 256 + threadIdx.x;
    if (idx < 294912) {                       // 256 n * 1152 groups
        int n = idx / 1152, g = idx - n * 1152;
        int ic = g / 9, r = g - ic * 9;
        const float* s = conv_w + n * 3456 + ic * 27 + r * 3;
        u16* d = Bp + n * 4608 + g * 4;
        d[0] = f2bf(s[0]); d[1] = f2bf(s[1]); d[2] = f2bf(s[2]); d[3] = 0;
    } else if (idx < 425984) {                // WkvP 512*256
        int i = idx - 294912;
        int n = i >> 8, c = i & 255;
        WkvP[i] = f2bf((n < 256) ? Wk[c * 256 + n] : Wv[c * 256 + (n - 256)]);
    } else if (idx < 491520) {                // WqP 256*256
        int i = idx - 425984;
        int n = i >> 8, c = i & 255;
        WqP[i] = f2bf(Wq[c * 256 + n]);
    } else if (idx < 622592) {                // W1T 512*256
        int i = idx - 491520;
        int h = i >> 8, c = i & 255;
        W1T[i] = f2bf(W1[c * 512 + h]);
    } else if (idx < 753664) {                // W2T 256*512
        int i = idx - 622592;
        int dd = i >> 9, h = i & 511;
        W2T[i] = f2bf(W2[h * 256 + dd]);
    }
}

// ============ fused conv3d(s2)+bias+ReLU+LN_in + k/v GEMM (R6 version) ============
__global__ __launch_bounds__(512, 4) void conv_fused(
    const float* __restrict__ x, const u16* __restrict__ Bp, const float* __restrict__ conv_b,
    const float* __restrict__ ln_g, const float* __restrict__ ln_b, const u16* __restrict__ WkvP,
    u16* __restrict__ kbuf, u16* __restrict__ vT)
{
    __shared__ __align__(16) char smem[66816];
    u16* slab0  = (u16*)smem;                 // [432 rows][36 iz] u16 = 31104 B
    u16* slab1  = (u16*)(smem + 31104);       // second buffer
    u16* tokbf  = (u16*)smem;                 // alias after conv: [64 m][264 c] = 33792 B
    float* lnred  = (float*)(smem + 62208);   // [8 w][64 m][2] = 4096
    float* lnstat = (float*)(smem + 66304);   // [64 m][2] = 512

    int blk = blockIdx.x;
    int b = blk & 7, ox = (blk >> 5) & 15, oyb = (blk >> 3) & 3;   // XCD pin: b = blk%8
    int tid = threadIdx.x, wid = tid >> 6, lane = tid & 63;
    int quad = lane >> 4, l15 = lane & 15;
    int nbase = wid * 32;                     // conv n-slice: 32 channels/wave

    f32x4 acc[4][2];
    #pragma unroll
    for (int i = 0; i < 4; ++i)
        #pragma unroll
        for (int j = 0; j < 2; ++j) acc[i][j] = ZERO4;

    const u16* bprow0 = Bp + (nbase + l15) * 4608 + quad * 8;
    const u16* bprow1 = bprow0 + 16 * 4608;

    const float* xp[8]; int so8[8]; unsigned wmask = 0;
    #pragma unroll
    for (int u = 0; u < 8; ++u) {
        int s = tid + u * 512;
        so8[u] = -1; xp[u] = x;
        if (s < 3888) {
            int row = s / 9;
            int c = s - row * 9;
            int icl = row / 27;
            int rr = row - icl * 27;
            int ixl = rr / 9;
            int iyl = rr - ixl * 9;
            const float* xr = x + ((size_t)((b * 128 + icl) * 33) + (2 * ox + ixl)) * 1089
                              + (8 * oyb + iyl) * 33;
            if (c < 8) { xp[u] = xr + c * 4; wmask |= (1u << u); }
            else       { xp[u] = xr + 32; }
            so8[u] = row * 36 + c * 4;
        }
    }
    const size_t ICST = 16ull * 35937;

    f32x4u tv[8];
#define LOADX(ICC)                                                          \
    {                                                                       \
        _Pragma("unroll")                                                   \
        for (int u = 0; u < 8; ++u) {                                       \
            if (so8[u] >= 0) {                                              \
                const float* p = xp[u] + (size_t)(ICC) * ICST;              \
                if ((wmask >> u) & 1u) tv[u] = *(const f32x4u*)p;           \
                else                   tv[u] = f32x4u{p[0], 0.f, 0.f, 0.f}; \
            }                                                               \
        }                                                                   \
    }
#define STOREX(DST)                                                         \
    {                                                                       \
        _Pragma("unroll")                                                   \
        for (int u = 0; u < 8; ++u) {                                       \
            if (so8[u] >= 0) {                                              \
                us4 w;                                                      \
                w.x = f2bf(tv[u].x); w.y = f2bf(tv[u].y);                   \
                w.z = f2bf(tv[u].z); w.w = f2bf(tv[u].w);                   \
                *(us4*)((DST) + so8[u]) = w;                                \
            }                                                               \
        }                                                                   \
    }

    LOADX(0)
    STOREX(slab0)
    __syncthreads();

    for (int icc = 0; icc < 8; ++icc) {
        const u16* cur = (icc & 1) ? slab1 : slab0;
        u16* nxt = (icc & 1) ? slab0 : slab1;
        if (icc < 7) LOADX(icc + 1)

        const u16* bk0 = bprow0 + icc * 576;
        const u16* bk1 = bprow1 + icc * 576;
        s16x8 bbA[2], bbB[2];
        bbA[0] = *reinterpret_cast<const s16x8*>(bk0);
        bbA[1] = *reinterpret_cast<const s16x8*>(bk1);

#define CONV_STEP(CC, BREG)                                                     \
        {                                                                       \
            int g = (CC) * 8 + quad * 2;                                        \
            int i0 = g / 9, r9 = g - i0 * 9;                                    \
            int kx = r9 / 3, ky = r9 - kx * 3;                                  \
            int base0 = (i0 * 27 + kx * 9 + ky) * 36 + 2 * l15;                 \
            g += 1;                                                             \
            i0 = g / 9; r9 = g - i0 * 9; kx = r9 / 3; ky = r9 - kx * 3;         \
            int base1 = (i0 * 27 + kx * 9 + ky) * 36 + 2 * l15;                 \
            _Pragma("unroll")                                                   \
            for (int fm = 0; fm < 4; ++fm) {                                    \
                union { s16x8 v; ushort2 h[4]; } af;                            \
                const u16* sp0 = cur + base0 + fm * 72;                         \
                const u16* sp1 = cur + base1 + fm * 72;                         \
                af.h[0] = *(const ushort2*)(sp0);                               \
                af.h[1] = *(const ushort2*)(sp0 + 2);                           \
                af.h[2] = *(const ushort2*)(sp1);                               \
                af.h[3] = *(const ushort2*)(sp1 + 2);                           \
                acc[fm][0] = mfma16(af.v, (BREG)[0], acc[fm][0]);               \
                acc[fm][1] = mfma16(af.v, (BREG)[1], acc[fm][1]);               \
            }                                                                   \
        }

        #pragma unroll 1
        for (int c8 = 0; c8 < 18; c8 += 2) {
            bbB[0] = *reinterpret_cast<const s16x8*>(bk0 + (c8 + 1) * 32);
            bbB[1] = *reinterpret_cast<const s16x8*>(bk1 + (c8 + 1) * 32);
            CONV_STEP(c8, bbA)
            if (c8 + 2 < 18) {
                bbA[0] = *reinterpret_cast<const s16x8*>(bk0 + (c8 + 2) * 32);
                bbA[1] = *reinterpret_cast<const s16x8*>(bk1 + (c8 + 2) * 32);
            }
            CONV_STEP(c8 + 1, bbB)
        }
#undef CONV_STEP
        if (icc < 7) STOREX(nxt)
        __syncthreads();
    }
#undef LOADX
#undef STOREX

    #pragma unroll
    for (int fn = 0; fn < 2; ++fn) {
        float bias = conv_b[nbase + fn * 16 + l15];
        #pragma unroll
        for (int fm = 0; fm < 4; ++fm)
            #pragma unroll
            for (int r = 0; r < 4; ++r)
                acc[fm][fn][r] = fmaxf(acc[fm][fn][r] + bias, 0.f);
    }
    #pragma unroll
    for (int fm = 0; fm < 4; ++fm) {
        #pragma unroll
        for (int r = 0; r < 4; ++r) {
            float s = acc[fm][0][r] + acc[fm][1][r];
            float q2 = acc[fm][0][r] * acc[fm][0][r] + acc[fm][1][r] * acc[fm][1][r];
            #pragma unroll
            for (int msk = 1; msk <= 8; msk <<= 1) {
                s  += __shfl_xor(s, msk, 64);
                q2 += __shfl_xor(q2, msk, 64);
            }
            if (l15 == 0) {
                int mm = fm * 16 + quad * 4 + r;
                lnred[(wid * 64 + mm) * 2 + 0] = s;
                lnred[(wid * 64 + mm) * 2 + 1] = q2;
            }
        }
    }
    __syncthreads();
    if (tid < 64) {
        float s = 0, q2 = 0;
        #pragma unroll
        for (int w = 0; w < 8; ++w) { s += lnred[(w * 64 + tid) * 2]; q2 += lnred[(w * 64 + tid) * 2 + 1]; }
        float mu = s * (1.f / 256.f);
        float var = fmaxf(q2 * (1.f / 256.f) - mu * mu, 0.f);
        lnstat[tid * 2]     = mu;
        lnstat[tid * 2 + 1] = rsqrtf(var + 1e-5f);
    }
    __syncthreads();
    {
        float gam[2], bet[2];
        #pragma unroll
        for (int fn = 0; fn < 2; ++fn) {
            int n = nbase + fn * 16 + l15;
            gam[fn] = ln_g[n]; bet[fn] = ln_b[n];
        }
        #pragma unroll
        for (int fm = 0; fm < 4; ++fm)
            #pragma unroll
            for (int r = 0; r < 4; ++r) {
                int mm = fm * 16 + quad * 4 + r;
                float mu = lnstat[mm * 2], rs = lnstat[mm * 2 + 1];
                #pragma unroll
                for (int fn = 0; fn < 2; ++fn) {
                    int n = nbase + fn * 16 + l15;
                    tokbf[mm * 264 + n] = f2bf((acc[fm][fn][r] - mu) * rs * gam[fn] + bet[fn]);
                }
            }
    }
    __syncthreads();
    f32x4 kacc[4][4];
    #pragma unroll
    for (int i = 0; i < 4; ++i)
        #pragma unroll
        for (int j = 0; j < 4; ++j) kacc[i][j] = ZERO4;
    int n2 = wid * 64;
    const u16* wp = WkvP + (n2 + l15) * 256 + quad * 8;
    s16x8 wvA[4], wvB[4];
    #pragma unroll
    for (int fn = 0; fn < 4; ++fn) wvA[fn] = *reinterpret_cast<const s16x8*>(wp + fn * 4096);

#define KV_STEP(KK, WREG)                                                           \
    {                                                                               \
        s16x8 a2[4];                                                                \
        _Pragma("unroll")                                                           \
        for (int fm = 0; fm < 4; ++fm)                                              \
            a2[fm] = *reinterpret_cast<const s16x8*>(tokbf + (fm * 16 + l15) * 264  \
                                                     + (KK) * 32 + quad * 8);       \
        _Pragma("unroll")                                                           \
        for (int fn = 0; fn < 4; ++fn)                                              \
            _Pragma("unroll")                                                       \
            for (int fm = 0; fm < 4; ++fm)                                          \
                kacc[fm][fn] = mfma16(a2[fm], (WREG)[fn], kacc[fm][fn]);            \
    }

    #pragma unroll 1
    for (int kc = 0; kc < 8; kc += 2) {
        #pragma unroll
        for (int fn = 0; fn < 4; ++fn)
            wvB[fn] = *reinterpret_cast<const s16x8*>(wp + fn * 4096 + (kc + 1) * 32);
        KV_STEP(kc, wvA)
        if (kc + 2 < 8) {
            #pragma unroll
            for (int fn = 0; fn < 4; ++fn)
                wvA[fn] = *reinterpret_cast<const s16x8*>(wp + fn * 4096 + (kc + 2) * 32);
        }
        KV_STEP(kc + 1, wvB)
    }
#undef KV_STEP

    #pragma unroll
    for (int fm = 0; fm < 4; ++fm)
        #pragma unroll
        for (int r = 0; r < 4; ++r) {
            int l = (ox * 16 + oyb * 4 + fm) * 16 + quad * 4 + r;
            #pragma unroll
            for (int fn = 0; fn < 4; ++fn) {
                int n = n2 + fn * 16 + l15;
                u16 v = f2bf(kacc[fm][fn][r]);
                if (n < 256) kbuf[((b << 12) + l) * 256 + n] = v;           // k[b][l][d]
                else         vT[((b * 256 + (n - 256)) << 12) + l] = v;     // vT[b][d][l]
            }
        }
}

// ============ kQ: init tpl; LN_t + q (iter 0); zero delta ============
__global__ __launch_bounds__(256) void kQ(
    const float* __restrict__ tinit, float* __restrict__ tpl,
    const float* __restrict__ ln_t_g, const float* __restrict__ ln_t_b,
    const u16* __restrict__ WqP, u16* __restrict__ qbuf, float* __restrict__ delta)
{
    __shared__ __align__(16) u16 mls[64 * 264];
    __shared__ float pls[64][4][2];
    __shared__ float stat[64][2];
    int b = blockIdx.x, tid = threadIdx.x;
    int m = tid >> 2, part = tid & 3;
    const float* tp = tinit + m * 256 + part * 64;
    float* tg = tpl + (b * 64 + m) * 256 + part * 64;
    float s = 0, q2 = 0;
    for (int i = 0; i < 64; ++i) {
        float v = tp[i];
        tg[i] = v;
        s += v; q2 += v * v;
    }
    pls[m][part][0] = s; pls[m][part][1] = q2;
    __syncthreads();
    if (tid < 64) {
        float ss = 0, qq = 0;
        #pragma unroll
        for (int p = 0; p < 4; ++p) { ss += pls[tid][p][0]; qq += pls[tid][p][1]; }
        float mu = ss * (1.f / 256.f);
        float var = fmaxf(qq * (1.f / 256.f) - mu * mu, 0.f);
        stat[tid][0] = mu; stat[tid][1] = rsqrtf(var + 1e-5f);
    }
    __syncthreads();
    {
        float mu = stat[m][0], rs = stat[m][1];
        for (int i = 0; i < 64; ++i) {
            int d = part * 64 + i;
            mls[m * 264 + d] = f2bf((tp[i] - mu) * rs * ln_t_g[d] + ln_t_b[d]);
        }
    }
    __syncthreads();
    int wid = tid >> 6, lane = tid & 63, quad = lane >> 4, l15 = lane & 15;
    f32x4 qa[4][4];
    #pragma unroll
    for (int i = 0; i < 4; ++i)
        #pragma unroll
        for (int j = 0; j < 4; ++j) qa[i][j] = ZERO4;
    #pragma unroll 1
    for (int kc = 0; kc < 8; ++kc) {
        s16x8 a[4];
        #pragma unroll
        for (int fm = 0; fm < 4; ++fm)
            a[fm] = *reinterpret_cast<const s16x8*>(mls + (fm * 16 + l15) * 264 + kc * 32 + quad * 8);
        #pragma unroll
        for (int fn = 0; fn < 4; ++fn) {
            s16x8 bv = *reinterpret_cast<const s16x8*>(WqP + (wid * 64 + fn * 16 + l15) * 256 + kc * 32 + quad * 8);
            #pragma unroll
            for (int fm = 0; fm < 4; ++fm)
                qa[fm][fn] = mfma16(a[fm], bv, qa[fm][fn]);
        }
    }
    #pragma unroll
    for (int fm = 0; fm < 4; ++fm)
        #pragma unroll
        for (int fn = 0; fn < 4; ++fn)
            #pragma unroll
            for (int r = 0; r < 4; ++r) {
                int mt = fm * 16 + quad * 4 + r;
                int d = wid * 64 + fn * 16 + l15;
                qbuf[(b * 64 + mt) * 256 + d] = f2bf(qa[fm][fn][r] * 0.0625f);
            }
    f32x4* dz = (f32x4*)(delta + b * 16384);
    for (int i = tid; i < 4096; i += 256) dz[i] = ZERO4;
}

// ============ kA<IT>: fused logits+softmax+PV; per-iter name for rocprof ============
template<int IT>
__global__ __launch_bounds__(512, 2) void kA(
    const u16* __restrict__ qbuf, const u16* __restrict__ kbuf, const u16* __restrict__ vT,
    float* __restrict__ cs_part, float* __restrict__ delta, u16* __restrict__ attnT)
{
    constexpr int last = (IT == 5);
    __shared__ __align__(16) u16 qls[64 * 264];       // 33792 B
    __shared__ __align__(16) u16 atile[64 * 136];     // 17408 B [n][l_local]
    __shared__ float colsh[8][64];                    // 2048 B
    int b = blockIdx.x & 7, ltg = blockIdx.x >> 3;    // XCD pin: b = blk%8
    int tid = threadIdx.x, wid = tid >> 6, lane = tid & 63;
    int quad = lane >> 4, l15 = lane & 15;

    // ---- stage q[b] (32 KB) into LDS ----
    {
        int r = tid >> 3, c = (tid & 7) * 32;
        const u16* src = qbuf + b * 16384 + r * 256 + c;
        u16* dst = qls + r * 264 + c;
        #pragma unroll
        for (int j = 0; j < 4; ++j)
            *(int4*)(dst + j * 8) = *(const int4*)(src + j * 8);
    }
    // ---- issue all k-row loads up-front ----
    int lrow = ltg * 128 + wid * 16;
    const u16* arow = kbuf + (size_t)((b << 12) + lrow + l15) * 256;
    s16x8 av[8];
    #pragma unroll
    for (int kc = 0; kc < 8; ++kc)
        av[kc] = *reinterpret_cast<const s16x8*>(arow + kc * 32 + quad * 8);
    // ---- issue vT loads for phase B now (hide latency under phase A) ----
    const u16* vrow = vT + ((size_t)(b * 256 + wid * 32 + l15) << 12) + ltg * 128 + quad * 8;
    s16x8 bv2[2][4];
    #pragma unroll
    for (int fn = 0; fn < 2; ++fn)
        #pragma unroll
        for (int kc = 0; kc < 4; ++kc)
            bv2[fn][kc] = *reinterpret_cast<const s16x8*>(vrow + (fn << 16) + kc * 32);
    __syncthreads();
    // ---- Phase A: QK^T + softmax(N) ----
    f32x4 sa[4];
    #pragma unroll
    for (int fn = 0; fn < 4; ++fn) sa[fn] = ZERO4;
    #pragma unroll
    for (int kc = 0; kc < 8; ++kc) {
        #pragma unroll
        for (int fn = 0; fn < 4; ++fn) {
            s16x8 bv = *reinterpret_cast<const s16x8*>(qls + (fn * 16 + l15) * 264 + kc * 32 + quad * 8);
            sa[fn] = mfma16(av[kc], bv, sa[fn]);
        }
    }
    float colp[4] = {0.f, 0.f, 0.f, 0.f};
    #pragma unroll
    for (int r = 0; r < 4; ++r) {
        float mx = fmaxf(fmaxf(sa[0][r], sa[1][r]), fmaxf(sa[2][r], sa[3][r]));
        #pragma unroll
        for (int msk = 1; msk <= 8; msk <<= 1) mx = fmaxf(mx, __shfl_xor(mx, msk, 64));
        float e[4], sum = 0;
        #pragma unroll
        for (int fn = 0; fn < 4; ++fn) { e[fn] = __expf(sa[fn][r] - mx); sum += e[fn]; }
        #pragma unroll
        for (int msk = 1; msk <= 8; msk <<= 1) sum += __shfl_xor(sum, msk, 64);
        float inv = 1.f / sum;
        #pragma unroll
        for (int fn = 0; fn < 4; ++fn) {
            float p = e[fn] * inv + 1e-8f;
            colp[fn] += p;
            atile[(fn * 16 + l15) * 136 + wid * 16 + quad * 4 + r] = f2bf(p);
        }
    }
    #pragma unroll
    for (int fn = 0; fn < 4; ++fn) {
        float c = colp[fn];
        c += __shfl_xor(c, 16, 64);
        c += __shfl_xor(c, 32, 64);
        if (lane < 16) colsh[wid][fn * 16 + lane] = c;
    }
    __syncthreads();
    if (tid < 64) {
        float s = 0;
        #pragma unroll
        for (int w = 0; w < 8; ++w) s += colsh[w][tid];
        cs_part[((b << 5) + ltg) * 64 + tid] = s;
    }
    // ---- Phase B: PV, K = this block's 128 l; atomics into delta ----
    {
        f32x4 pacc[4][2];
        #pragma unroll
        for (int i = 0; i < 4; ++i)
            #pragma unroll
            for (int j = 0; j < 2; ++j) pacc[i][j] = ZERO4;
        #pragma unroll
        for (int kc = 0; kc < 4; ++kc) {
            #pragma unroll
            for (int fm = 0; fm < 4; ++fm) {
                s16x8 a = *reinterpret_cast<const s16x8*>(atile + (fm * 16 + l15) * 136 + kc * 32 + quad * 8);
                #pragma unroll
                for (int fn = 0; fn < 2; ++fn)
                    pacc[fm][fn] = mfma16(a, bv2[fn][kc], pacc[fm][fn]);
            }
        }
        #pragma unroll
        for (int fm = 0; fm < 4; ++fm)
            #pragma unroll
            for (int fn = 0; fn < 2; ++fn)
                #pragma unroll
                for (int r = 0; r < 4; ++r) {
                    int n = fm * 16 + quad * 4 + r;
                    int d = wid * 32 + fn * 16 + l15;
                    atomicAdd(&delta[(size_t)(b * 64 + n) * 256 + d], pacc[fm][fn][r]);
                }
    }
    // ---- Phase C: P tile -> attnT on last iter only ----
    if (last) {
        int n = tid >> 3, lo = (tid & 7) * 16;
        const u16* src = atile + n * 136 + lo;
        u16* dst = attnT + (size_t)((b * 64 + n) << 12) + ltg * 128 + lo;
        *(int4*)(dst)     = *(const int4*)(src);
        *(int4*)(dst + 8) = *(const int4*)(src + 8);
    }
}

// ============ kT<IT>: template update; per-iter name for rocprof ============
template<int IT>
__global__ __launch_bounds__(512) void kT(
    float* __restrict__ tpl, float* __restrict__ delta, const float* __restrict__ cs_part,
    float* __restrict__ colsum,
    const float* __restrict__ ln_m_g, const float* __restrict__ ln_m_b,
    const u16* __restrict__ W1T, const float* __restrict__ b1,
    const u16* __restrict__ W2T, const float* __restrict__ b2,
    const float* __restrict__ ln_t_g, const float* __restrict__ ln_t_b,
    const u16* __restrict__ WqP, u16* __restrict__ qbuf,
    float* __restrict__ out0)
{
    constexpr int last = (IT == 5);
    __shared__ __align__(16) u16 mls[16 * 264];      // 8448
    __shared__ __align__(16) u16 hid[16 * 520];      // 16640
    __shared__ float pls[16][32][2];                 // 4096
    __shared__ float stat[16][2];
    __shared__ float lnr2[8][16][2];                 // 1024
    __shared__ float csh[16];
    int b = blockIdx.x & 7, mg = blockIdx.x >> 3;    // XCD pin: b = blk%8
    int m0 = mg * 16;
    int tid = threadIdx.x, wid = tid >> 6, lane = tid & 63;
    int quad = lane >> 4, l15 = lane & 15;
    // ---- phase 0: reduce colsum partials ----
    if (tid < 16) {
        float s = 0;
        #pragma unroll
        for (int g = 0; g < 32; ++g) s += cs_part[((b << 5) + g) * 64 + m0 + tid];
        csh[tid] = 1.f / s;
        if (last) colsum[b * 64 + m0 + tid] = s;
    }
    __syncthreads();
    // ---- phase 1: v = tpl + delta/colsum; zero delta; LN_m -> mls; tpl = v ----
    {
        int ml = tid >> 5, part = tid & 31;
        float cinv = csh[ml];
        float* tg = tpl + (b * 64 + m0 + ml) * 256 + part * 8;
        float* dg = delta + (size_t)(b * 64 + m0 + ml) * 256 + part * 8;
        float vbuf[8];
        float s = 0, q2 = 0;
        #pragma unroll
        for (int i = 0; i < 8; ++i) {
            float v = tg[i] + dg[i] * cinv;
            vbuf[i] = v; s += v; q2 += v * v;
        }
        if (!last) {
            f32x4* dz = (f32x4*)dg;
            dz[0] = ZERO4; dz[1] = ZERO4;
        }
        pls[ml][part][0] = s; pls[ml][part][1] = q2;
        __syncthreads();
        if (tid < 16) {
            float ss = 0, qq = 0;
            #pragma unroll
            for (int p = 0; p < 32; ++p) { ss += pls[tid][p][0]; qq += pls[tid][p][1]; }
            float mu = ss * (1.f / 256.f);
            float var = fmaxf(qq * (1.f / 256.f) - mu * mu, 0.f);
            stat[tid][0] = mu; stat[tid][1] = rsqrtf(var + 1e-5f);
        }
        __syncthreads();
        float mu = stat[ml][0], rs = stat[ml][1];
        #pragma unroll
        for (int i = 0; i < 8; ++i) {
            int d = part * 8 + i;
            tg[i] = vbuf[i];
            mls[ml * 264 + d] = f2bf((vbuf[i] - mu) * rs * ln_m_g[d] + ln_m_b[d]);
        }
    }
    __syncthreads();
    // ---- G1: hid = gelu(mls @ W1 + b1); 8 waves, wave -> 64 nh ----
    {
        f32x4 ha[4];
        #pragma unroll
        for (int j = 0; j < 4; ++j) ha[j] = ZERO4;
        #pragma unroll 1
        for (int kc = 0; kc < 8; ++kc) {
            s16x8 a = *reinterpret_cast<const s16x8*>(mls + l15 * 264 + kc * 32 + quad * 8);
            #pragma unroll
            for (int fn = 0; fn < 4; ++fn) {
                s16x8 bv = *reinterpret_cast<const s16x8*>(W1T + (wid * 64 + fn * 16 + l15) * 256 + kc * 32 + quad * 8);
                ha[fn] = mfma16(a, bv, ha[fn]);
            }
        }
        #pragma unroll
        for (int fn = 0; fn < 4; ++fn) {
            int nh = wid * 64 + fn * 16 + l15;
            float bb = b1[nh];
            #pragma unroll
            for (int r = 0; r < 4; ++r) {
                float v = ha[fn][r] + bb;
                v = 0.5f * v * (1.f + erff(v * 0.70710678118654752f));
                hid[(quad * 4 + r) * 520 + nh] = f2bf(v);
            }
        }
    }
    __syncthreads();
    // ---- G2: new = tpl + hid @ W2 + b2; LN_t -> mls; out0 on last; wave -> 32 d ----
    {
        f32x4 oa[2];
        oa[0] = ZERO4; oa[1] = ZERO4;
        #pragma unroll 1
        for (int kc = 0; kc < 16; ++kc) {
            s16x8 a = *reinterpret_cast<const s16x8*>(hid + l15 * 520 + kc * 32 + quad * 8);
            #pragma unroll
            for (int fn = 0; fn < 2; ++fn) {
                s16x8 bv = *reinterpret_cast<const s16x8*>(W2T + (wid * 32 + fn * 16 + l15) * 512 + kc * 32 + quad * 8);
                oa[fn] = mfma16(a, bv, oa[fn]);
            }
        }
        #pragma unroll
        for (int fn = 0; fn < 2; ++fn) {
            int d = wid * 32 + fn * 16 + l15;
            float bb = b2[d];
            #pragma unroll
            for (int r = 0; r < 4; ++r) {
                int mm = quad * 4 + r;
                oa[fn][r] += bb + tpl[(b * 64 + m0 + mm) * 256 + d];
            }
        }
        #pragma unroll
        for (int r = 0; r < 4; ++r) {
            float s = oa[0][r] + oa[1][r];
            float q2 = oa[0][r] * oa[0][r] + oa[1][r] * oa[1][r];
            #pragma unroll
            for (int msk = 1; msk <= 8; msk <<= 1) {
                s  += __shfl_xor(s, msk, 64);
                q2 += __shfl_xor(q2, msk, 64);
            }
            if (l15 == 0) {
                lnr2[wid][quad * 4 + r][0] = s;
                lnr2[wid][quad * 4 + r][1] = q2;
            }
        }
        __syncthreads();
        if (tid < 16) {
            float ss = 0, qq = 0;
            #pragma unroll
            for (int w = 0; w < 8; ++w) { ss += lnr2[w][tid][0]; qq += lnr2[w][tid][1]; }
            float mu = ss * (1.f / 256.f);
            float var = fmaxf(qq * (1.f / 256.f) - mu * mu, 0.f);
            stat[tid][0] = mu; stat[tid][1] = rsqrtf(var + 1e-5f);
        }
        __syncthreads();
        #pragma unroll
        for (int fn = 0; fn < 2; ++fn) {
            int d = wid * 32 + fn * 16 + l15;
            float gg = last ? 0.f : ln_t_g[d];
            float bt = last ? 0.f : ln_t_b[d];
            #pragma unroll
            for (int r = 0; r < 4; ++r) {
                int mm = quad * 4 + r;
                float v = oa[fn][r];
                tpl[(b * 64 + m0 + mm) * 256 + d] = v;
                if (last) {
                    out0[(b * 256 + d) * 64 + m0 + mm] = v;
                } else {
                    mls[mm * 264 + d] = f2bf((v - stat[mm][0]) * stat[mm][1] * gg + bt);
                }
            }
        }
    }
    if (!last) {
        __syncthreads();
        // ---- q-GEMM for next iteration; wave -> 32 d ----
        f32x4 qa[2];
        qa[0] = ZERO4; qa[1] = ZERO4;
        #pragma unroll 1
        for (int kc = 0; kc < 8; ++kc) {
            s16x8 a = *reinterpret_cast<const s16x8*>(mls + l15 * 264 + kc * 32 + quad * 8);
            #pragma unroll
            for (int fn = 0; fn < 2; ++fn) {
                s16x8 bv = *reinterpret_cast<const s16x8*>(WqP + (wid * 32 + fn * 16 + l15) * 256 + kc * 32 + quad * 8);
                qa[fn] = mfma16(a, bv, qa[fn]);
            }
        }
        #pragma unroll
        for (int fn = 0; fn < 2; ++fn)
            #pragma unroll
            for (int r = 0; r < 4; ++r) {
                int mt = m0 + quad * 4 + r;
                int d = wid * 32 + fn * 16 + l15;
                qbuf[(b * 64 + mt) * 256 + d] = f2bf(qa[fn][r] * 0.0625f);
            }
    }
}

// ============ kE: attn_out = attnT / colsum; b = blk&7 (XCD-pinned) ============
__global__ void kE(const u16* __restrict__ attnT, const float* __restrict__ colsum,
                   float* __restrict__ out1)
{
    int blk = blockIdx.x;
    int b = blk & 7, r8 = blk >> 3;                  // XCD pin: b = blk%8
    int e = (b << 18) + (r8 << 10) + threadIdx.x * 4;
    int n = (e >> 12) & 63;
    float ci = 1.f / colsum[b * 64 + n];
    const u16* s = attnT + e;
    f32x4 o;
    o.x = bf2f(s[0]) * ci; o.y = bf2f(s[1]) * ci;
    o.z = bf2f(s[2]) * ci; o.w = bf2f(s[3]) * ci;
    *(f32x4*)(out1 + e) = o;
}

// ============ launch ============
extern "C" void kernel_launch(void* const* d_in, const int* in_sizes, int n_in,
                              void* d_out, int out_size, void* d_ws, size_t ws_size,
                              hipStream_t stream)
{
    const float* x       = (const float*)d_in[0];
    const float* tinit   = (const float*)d_in[1];
    const float* conv_w  = (const float*)d_in[2];
    const float* conv_b  = (const float*)d_in[3];
    const float* Wq      = (const float*)d_in[4];
    const float* Wk      = (const float*)d_in[5];
    const float* Wv      = (const float*)d_in[6];
    const float* ln_in_g = (const float*)d_in[7];
    const float* ln_in_b = (const float*)d_in[8];
    const float* ln_t_g  = (const float*)d_in[9];
    const float* ln_t_b  = (const float*)d_in[10];
    const float* ln_m_g  = (const float*)d_in[11];
    const float* ln_m_b  = (const float*)d_in[12];
    const float* W1      = (const float*)d_in[13];
    const float* b1      = (const float*)d_in[14];
    const float* W2      = (const float*)d_in[15];
    const float* b2      = (const float*)d_in[16];

    char* ws = (char*)d_ws;
    u16* Bp       = (u16*)(ws + 0);          // 2,359,296
    u16* WkvP     = (u16*)(ws + 2359296);    //   262,144
    u16* WqP      = (u16*)(ws + 2621440);    //   131,072
    u16* W1T      = (u16*)(ws + 2752512);    //   262,144
    u16* W2T      = (u16*)(ws + 3014656);    //   262,144
    u16* kbuf     = (u16*)(ws + 3276800);    // 16,777,216
    u16* vT       = (u16*)(ws + 20054016);   // 16,777,216
    u16* qbuf     = (u16*)(ws + 36831232);   //   262,144
    u16* attnT    = (u16*)(ws + 37093376);   // 4,194,304  (written last iter only)
    float* colsum = (float*)(ws + 41287680); //     2,048
    float* tpl    = (float*)(ws + 41289728); //   524,288
    float* delta  = (float*)(ws + 41814016); //   524,288
    float* cs_part= (float*)(ws + 42338304); //    65,536   (total ~42.4 MB)

    float* out0 = (float*)d_out;      // templates_out (8,256,64)
    float* out1 = out0 + 131072;      // attn_out (8,64,16,16,16)

    prepack_kernel<<<2944, 256, 0, stream>>>(conv_w, Wk, Wv, Wq, W1, W2, Bp, WkvP, WqP, W1T, W2T);
    conv_fused<<<512, 512, 0, stream>>>(x, Bp, conv_b, ln_in_g, ln_in_b, WkvP, kbuf, vT);
    kQ<<<8, 256, 0, stream>>>(tinit, tpl, ln_t_g, ln_t_b, WqP, qbuf, delta);

#define LOOP_IT(IT)                                                                       \
    kA<IT><<<256, 512, 0, stream>>>(qbuf, kbuf, vT, cs_part, delta, attnT);               \
    kT<IT><<<32, 512, 0, stream>>>(tpl, delta, cs_part, colsum, ln_m_g, ln_m_b, W1T, b1,  \
                                   W2T, b2, ln_t_g, ln_t_b, WqP, qbuf, out0);
    LOOP_IT(0)
    LOOP_IT(1)
    LOOP_IT(2)
    LOOP_IT(3)
    LOOP_IT(4)
    LOOP_IT(5)
#undef LOOP_IT

    kE<<<2048, 256, 0, stream>>>(attnT, colsum, out1);
}

// Round 9
// 741.413 us; speedup vs baseline: 1.9736x; 1.0765x over previous
//
#include <hip/hip_runtime.h>

typedef unsigned short u16;
typedef short s16x8 __attribute__((ext_vector_type(8)));
typedef float f32x4 __attribute__((ext_vector_type(4)));
typedef float f32x4u __attribute__((ext_vector_type(4), aligned(4)));
typedef unsigned short us4 __attribute__((ext_vector_type(4)));   // 8 B

__device__ __forceinline__ float bf2f(u16 v) {
    return __uint_as_float(((unsigned int)v) << 16);
}
__device__ __forceinline__ u16 f2bf(float f) {
    unsigned int u = __float_as_uint(f);
    u = u + 0x7FFFu + ((u >> 16) & 1u);
    return (u16)(u >> 16);
}
__device__ __forceinline__ f32x4 mfma16(s16x8 a, s16x8 b, f32x4 c) {
    return __builtin_amdgcn_mfma_f32_16x16x32_bf16(a, b, c, 0, 0, 0);
}
#define ZERO4 f32x4{0.f, 0.f, 0.f, 0.f}

// ============ prepack: f32 weights -> bf16 MFMA B-fragment layouts ============
__global__ void prepack_kernel(const float* __restrict__ conv_w, const float* __restrict__ Wk,
                               const float* __restrict__ Wv, const float* __restrict__ Wq,
                               const float* __restrict__ W1, const float* __restrict__ W2,
                               u16* __restrict__ Bp, u16* __restrict__ WkvP, u16* __restrict__ WqP,
                               u16* __restrict__ W1T, u16* __restrict__ W2T)
{
    int idx = blockIdx.x * 256 + threadIdx.x;
    if (idx < 294912) {                       // 256 n * 1152 groups
        int n = idx / 1152, g = idx - n * 1152;
        int ic = g / 9, r = g - ic * 9;
        const float* s = conv_w + n * 3456 + ic * 27 + r * 3;
        u16* d = Bp + n * 4608 + g * 4;
        d[0] = f2bf(s[0]); d[1] = f2bf(s[1]); d[2] = f2bf(s[2]); d[3] = 0;
    } else if (idx < 425984) {                // WkvP 512*256
        int i = idx - 294912;
        int n = i >> 8, c = i & 255;
        WkvP[i] = f2bf((n < 256) ? Wk[c * 256 + n] : Wv[c * 256 + (n - 256)]);
    } else if (idx < 491520) {                // WqP 256*256
        int i = idx - 425984;
        int n = i >> 8, c = i & 255;
        WqP[i] = f2bf(Wq[c * 256 + n]);
    } else if (idx < 622592) {                // W1T 512*256
        int i = idx - 491520;
        int h = i >> 8, c = i & 255;
        W1T[i] = f2bf(W1[c * 512 + h]);
    } else if (idx < 753664) {                // W2T 256*512
        int i = idx - 622592;
        int dd = i >> 9, h = i & 511;
        W2T[i] = f2bf(W2[h * 256 + dd]);
    }
}

// ============ fused conv3d(s2)+bias+ReLU+LN_in + k/v GEMM (R6 version) ============
__global__ __launch_bounds__(512, 4) void conv_fused(
    const float* __restrict__ x, const u16* __restrict__ Bp, const float* __restrict__ conv_b,
    const float* __restrict__ ln_g, const float* __restrict__ ln_b, const u16* __restrict__ WkvP,
    u16* __restrict__ kbuf, u16* __restrict__ vT)
{
    __shared__ __align__(16) char smem[66816];
    u16* slab0  = (u16*)smem;                 // [432 rows][36 iz] u16 = 31104 B
    u16* slab1  = (u16*)(smem + 31104);       // second buffer
    u16* tokbf  = (u16*)smem;                 // alias after conv: [64 m][264 c] = 33792 B
    float* lnred  = (float*)(smem + 62208);   // [8 w][64 m][2] = 4096
    float* lnstat = (float*)(smem + 66304);   // [64 m][2] = 512

    int blk = blockIdx.x;
    int b = blk & 7, ox = (blk >> 5) & 15, oyb = (blk >> 3) & 3;   // XCD pin: b = blk%8
    int tid = threadIdx.x, wid = tid >> 6, lane = tid & 63;
    int quad = lane >> 4, l15 = lane & 15;
    int nbase = wid * 32;                     // conv n-slice: 32 channels/wave

    f32x4 acc[4][2];
    #pragma unroll
    for (int i = 0; i < 4; ++i)
        #pragma unroll
        for (int j = 0; j < 2; ++j) acc[i][j] = ZERO4;

    const u16* bprow0 = Bp + (nbase + l15) * 4608 + quad * 8;
    const u16* bprow1 = bprow0 + 16 * 4608;

    const float* xp[8]; int so8[8]; unsigned wmask = 0;
    #pragma unroll
    for (int u = 0; u < 8; ++u) {
        int s = tid + u * 512;
        so8[u] = -1; xp[u] = x;
        if (s < 3888) {
            int row = s / 9;
            int c = s - row * 9;
            int icl = row / 27;
            int rr = row - icl * 27;
            int ixl = rr / 9;
            int iyl = rr - ixl * 9;
            const float* xr = x + ((size_t)((b * 128 + icl) * 33) + (2 * ox + ixl)) * 1089
                              + (8 * oyb + iyl) * 33;
            if (c < 8) { xp[u] = xr + c * 4; wmask |= (1u << u); }
            else       { xp[u] = xr + 32; }
            so8[u] = row * 36 + c * 4;
        }
    }
    const size_t ICST = 16ull * 35937;

    f32x4u tv[8];
#define LOADX(ICC)                                                          \
    {                                                                       \
        _Pragma("unroll")                                                   \
        for (int u = 0; u < 8; ++u) {                                       \
            if (so8[u] >= 0) {                                              \
                const float* p = xp[u] + (size_t)(ICC) * ICST;              \
                if ((wmask >> u) & 1u) tv[u] = *(const f32x4u*)p;           \
                else                   tv[u] = f32x4u{p[0], 0.f, 0.f, 0.f}; \
            }                                                               \
        }                                                                   \
    }
#define STOREX(DST)                                                         \
    {                                                                       \
        _Pragma("unroll")                                                   \
        for (int u = 0; u < 8; ++u) {                                       \
            if (so8[u] >= 0) {                                              \
                us4 w;                                                      \
                w.x = f2bf(tv[u].x); w.y = f2bf(tv[u].y);                   \
                w.z = f2bf(tv[u].z); w.w = f2bf(tv[u].w);                   \
                *(us4*)((DST) + so8[u]) = w;                                \
            }                                                               \
        }                                                                   \
    }

    LOADX(0)
    STOREX(slab0)
    __syncthreads();

    for (int icc = 0; icc < 8; ++icc) {
        const u16* cur = (icc & 1) ? slab1 : slab0;
        u16* nxt = (icc & 1) ? slab0 : slab1;
        if (icc < 7) LOADX(icc + 1)

        const u16* bk0 = bprow0 + icc * 576;
        const u16* bk1 = bprow1 + icc * 576;
        s16x8 bbA[2], bbB[2];
        bbA[0] = *reinterpret_cast<const s16x8*>(bk0);
        bbA[1] = *reinterpret_cast<const s16x8*>(bk1);

#define CONV_STEP(CC, BREG)                                                     \
        {                                                                       \
            int g = (CC) * 8 + quad * 2;                                        \
            int i0 = g / 9, r9 = g - i0 * 9;                                    \
            int kx = r9 / 3, ky = r9 - kx * 3;                                  \
            int base0 = (i0 * 27 + kx * 9 + ky) * 36 + 2 * l15;                 \
            g += 1;                                                             \
            i0 = g / 9; r9 = g - i0 * 9; kx = r9 / 3; ky = r9 - kx * 3;         \
            int base1 = (i0 * 27 + kx * 9 + ky) * 36 + 2 * l15;                 \
            _Pragma("unroll")                                                   \
            for (int fm = 0; fm < 4; ++fm) {                                    \
                union { s16x8 v; ushort2 h[4]; } af;                            \
                const u16* sp0 = cur + base0 + fm * 72;                         \
                const u16* sp1 = cur + base1 + fm * 72;                         \
                af.h[0] = *(const ushort2*)(sp0);                               \
                af.h[1] = *(const ushort2*)(sp0 + 2);                           \
                af.h[2] = *(const ushort2*)(sp1);                               \
                af.h[3] = *(const ushort2*)(sp1 + 2);                           \
                acc[fm][0] = mfma16(af.v, (BREG)[0], acc[fm][0]);               \
                acc[fm][1] = mfma16(af.v, (BREG)[1], acc[fm][1]);               \
            }                                                                   \
        }

        #pragma unroll 1
        for (int c8 = 0; c8 < 18; c8 += 2) {
            bbB[0] = *reinterpret_cast<const s16x8*>(bk0 + (c8 + 1) * 32);
            bbB[1] = *reinterpret_cast<const s16x8*>(bk1 + (c8 + 1) * 32);
            CONV_STEP(c8, bbA)
            if (c8 + 2 < 18) {
                bbA[0] = *reinterpret_cast<const s16x8*>(bk0 + (c8 + 2) * 32);
                bbA[1] = *reinterpret_cast<const s16x8*>(bk1 + (c8 + 2) * 32);
            }
            CONV_STEP(c8 + 1, bbB)
        }
#undef CONV_STEP
        if (icc < 7) STOREX(nxt)
        __syncthreads();
    }
#undef LOADX
#undef STOREX

    #pragma unroll
    for (int fn = 0; fn < 2; ++fn) {
        float bias = conv_b[nbase + fn * 16 + l15];
        #pragma unroll
        for (int fm = 0; fm < 4; ++fm)
            #pragma unroll
            for (int r = 0; r < 4; ++r)
                acc[fm][fn][r] = fmaxf(acc[fm][fn][r] + bias, 0.f);
    }
    #pragma unroll
    for (int fm = 0; fm < 4; ++fm) {
        #pragma unroll
        for (int r = 0; r < 4; ++r) {
            float s = acc[fm][0][r] + acc[fm][1][r];
            float q2 = acc[fm][0][r] * acc[fm][0][r] + acc[fm][1][r] * acc[fm][1][r];
            #pragma unroll
            for (int msk = 1; msk <= 8; msk <<= 1) {
                s  += __shfl_xor(s, msk, 64);
                q2 += __shfl_xor(q2, msk, 64);
            }
            if (l15 == 0) {
                int mm = fm * 16 + quad * 4 + r;
                lnred[(wid * 64 + mm) * 2 + 0] = s;
                lnred[(wid * 64 + mm) * 2 + 1] = q2;
            }
        }
    }
    __syncthreads();
    if (tid < 64) {
        float s = 0, q2 = 0;
        #pragma unroll
        for (int w = 0; w < 8; ++w) { s += lnred[(w * 64 + tid) * 2]; q2 += lnred[(w * 64 + tid) * 2 + 1]; }
        float mu = s * (1.f / 256.f);
        float var = fmaxf(q2 * (1.f / 256.f) - mu * mu, 0.f);
        lnstat[tid * 2]     = mu;
        lnstat[tid * 2 + 1] = rsqrtf(var + 1e-5f);
    }
    __syncthreads();
    {
        float gam[2], bet[2];
        #pragma unroll
        for (int fn = 0; fn < 2; ++fn) {
            int n = nbase + fn * 16 + l15;
            gam[fn] = ln_g[n]; bet[fn] = ln_b[n];
        }
        #pragma unroll
        for (int fm = 0; fm < 4; ++fm)
            #pragma unroll
            for (int r = 0; r < 4; ++r) {
                int mm = fm * 16 + quad * 4 + r;
                float mu = lnstat[mm * 2], rs = lnstat[mm * 2 + 1];
                #pragma unroll
                for (int fn = 0; fn < 2; ++fn) {
                    int n = nbase + fn * 16 + l15;
                    tokbf[mm * 264 + n] = f2bf((acc[fm][fn][r] - mu) * rs * gam[fn] + bet[fn]);
                }
            }
    }
    __syncthreads();
    f32x4 kacc[4][4];
    #pragma unroll
    for (int i = 0; i < 4; ++i)
        #pragma unroll
        for (int j = 0; j < 4; ++j) kacc[i][j] = ZERO4;
    int n2 = wid * 64;
    const u16* wp = WkvP + (n2 + l15) * 256 + quad * 8;
    s16x8 wvA[4], wvB[4];
    #pragma unroll
    for (int fn = 0; fn < 4; ++fn) wvA[fn] = *reinterpret_cast<const s16x8*>(wp + fn * 4096);

#define KV_STEP(KK, WREG)                                                           \
    {                                                                               \
        s16x8 a2[4];                                                                \
        _Pragma("unroll")                                                           \
        for (int fm = 0; fm < 4; ++fm)                                              \
            a2[fm] = *reinterpret_cast<const s16x8*>(tokbf + (fm * 16 + l15) * 264  \
                                                     + (KK) * 32 + quad * 8);       \
        _Pragma("unroll")                                                           \
        for (int fn = 0; fn < 4; ++fn)                                              \
            _Pragma("unroll")                                                       \
            for (int fm = 0; fm < 4; ++fm)                                          \
                kacc[fm][fn] = mfma16(a2[fm], (WREG)[fn], kacc[fm][fn]);            \
    }

    #pragma unroll 1
    for (int kc = 0; kc < 8; kc += 2) {
        #pragma unroll
        for (int fn = 0; fn < 4; ++fn)
            wvB[fn] = *reinterpret_cast<const s16x8*>(wp + fn * 4096 + (kc + 1) * 32);
        KV_STEP(kc, wvA)
        if (kc + 2 < 8) {
            #pragma unroll
            for (int fn = 0; fn < 4; ++fn)
                wvA[fn] = *reinterpret_cast<const s16x8*>(wp + fn * 4096 + (kc + 2) * 32);
        }
        KV_STEP(kc + 1, wvB)
    }
#undef KV_STEP

    #pragma unroll
    for (int fm = 0; fm < 4; ++fm)
        #pragma unroll
        for (int r = 0; r < 4; ++r) {
            int l = (ox * 16 + oyb * 4 + fm) * 16 + quad * 4 + r;
            #pragma unroll
            for (int fn = 0; fn < 4; ++fn) {
                int n = n2 + fn * 16 + l15;
                u16 v = f2bf(kacc[fm][fn][r]);
                if (n < 256) kbuf[((b << 12) + l) * 256 + n] = v;           // k[b][l][d]
                else         vT[((b * 256 + (n - 256)) << 12) + l] = v;     // vT[b][d][l]
            }
        }
}

// ============ kQ: init tpl; LN_t + q (iter 0); zero delta ============
__global__ __launch_bounds__(256) void kQ(
    const float* __restrict__ tinit, float* __restrict__ tpl,
    const float* __restrict__ ln_t_g, const float* __restrict__ ln_t_b,
    const u16* __restrict__ WqP, u16* __restrict__ qbuf, float* __restrict__ delta)
{
    __shared__ __align__(16) u16 mls[64 * 264];
    __shared__ float pls[64][4][2];
    __shared__ float stat[64][2];
    int b = blockIdx.x, tid = threadIdx.x;
    int m = tid >> 2, part = tid & 3;
    const float* tp = tinit + m * 256 + part * 64;
    float* tg = tpl + (b * 64 + m) * 256 + part * 64;
    float s = 0, q2 = 0;
    for (int i = 0; i < 64; ++i) {
        float v = tp[i];
        tg[i] = v;
        s += v; q2 += v * v;
    }
    pls[m][part][0] = s; pls[m][part][1] = q2;
    __syncthreads();
    if (tid < 64) {
        float ss = 0, qq = 0;
        #pragma unroll
        for (int p = 0; p < 4; ++p) { ss += pls[tid][p][0]; qq += pls[tid][p][1]; }
        float mu = ss * (1.f / 256.f);
        float var = fmaxf(qq * (1.f / 256.f) - mu * mu, 0.f);
        stat[tid][0] = mu; stat[tid][1] = rsqrtf(var + 1e-5f);
    }
    __syncthreads();
    {
        float mu = stat[m][0], rs = stat[m][1];
        for (int i = 0; i < 64; ++i) {
            int d = part * 64 + i;
            mls[m * 264 + d] = f2bf((tp[i] - mu) * rs * ln_t_g[d] + ln_t_b[d]);
        }
    }
    __syncthreads();
    int wid = tid >> 6, lane = tid & 63, quad = lane >> 4, l15 = lane & 15;
    f32x4 qa[4][4];
    #pragma unroll
    for (int i = 0; i < 4; ++i)
        #pragma unroll
        for (int j = 0; j < 4; ++j) qa[i][j] = ZERO4;
    #pragma unroll 1
    for (int kc = 0; kc < 8; ++kc) {
        s16x8 a[4];
        #pragma unroll
        for (int fm = 0; fm < 4; ++fm)
            a[fm] = *reinterpret_cast<const s16x8*>(mls + (fm * 16 + l15) * 264 + kc * 32 + quad * 8);
        #pragma unroll
        for (int fn = 0; fn < 4; ++fn) {
            s16x8 bv = *reinterpret_cast<const s16x8*>(WqP + (wid * 64 + fn * 16 + l15) * 256 + kc * 32 + quad * 8);
            #pragma unroll
            for (int fm = 0; fm < 4; ++fm)
                qa[fm][fn] = mfma16(a[fm], bv, qa[fm][fn]);
        }
    }
    #pragma unroll
    for (int fm = 0; fm < 4; ++fm)
        #pragma unroll
        for (int fn = 0; fn < 4; ++fn)
            #pragma unroll
            for (int r = 0; r < 4; ++r) {
                int mt = fm * 16 + quad * 4 + r;
                int d = wid * 64 + fn * 16 + l15;
                qbuf[(b * 64 + mt) * 256 + d] = f2bf(qa[fm][fn][r] * 0.0625f);
            }
    f32x4* dz = (f32x4*)(delta + b * 16384);
    for (int i = tid; i < 4096; i += 256) dz[i] = ZERO4;
}

// ============ kA: fused logits+softmax+PV; grid 256 x 1024 threads (16 waves/CU) ============
// Wave (rowgrp = wid&7, fnh = wid>>3): QK^T for 16 k-rows x 32 n. Softmax max/sum combined
// across wave pairs via LDS. PV: each of 16 waves owns a 16-d slice (16 atomics/thread).
__global__ __launch_bounds__(1024, 1) void kA(
    const u16* __restrict__ qbuf, const u16* __restrict__ kbuf, const u16* __restrict__ vT,
    float* __restrict__ cs_part, float* __restrict__ delta, int last, u16* __restrict__ attnT)
{
    __shared__ __align__(16) u16 qls[64 * 264];       // 33792 B
    __shared__ __align__(16) u16 atile[64 * 136];     // 17408 B [n][l_local]
    __shared__ float colsh[64][8];                    // 2048 B
    __shared__ float smx[8][2][16];                   // 1024 B
    __shared__ float ssm[8][2][16];                   // 1024 B
    int b = blockIdx.x & 7, ltg = blockIdx.x >> 3;    // XCD pin: b = blk%8; ltg 0..31
    int tid = threadIdx.x, wid = tid >> 6, lane = tid & 63;
    int quad = lane >> 4, l15 = lane & 15;
    int rowgrp = wid & 7, fnh = wid >> 3;

    // ---- stage q[b] (32 KB) into LDS: 1024 threads x 32 B ----
    {
        int r = tid >> 4, c = (tid & 15) * 16;
        const u16* src = qbuf + b * 16384 + r * 256 + c;
        u16* dst = qls + r * 264 + c;
        *(int4*)(dst)     = *(const int4*)(src);
        *(int4*)(dst + 8) = *(const int4*)(src + 8);
    }
    // ---- k-row fragments (16 rows per wave) ----
    int lrow = ltg * 128 + rowgrp * 16;
    const u16* arow = kbuf + (size_t)((b << 12) + lrow + l15) * 256;
    s16x8 av[8];
    #pragma unroll
    for (int kc = 0; kc < 8; ++kc)
        av[kc] = *reinterpret_cast<const s16x8*>(arow + kc * 32 + quad * 8);
    // ---- vT loads for PV (wave owns d-slice wid*16..+15), hidden under phase A ----
    const u16* vrow = vT + ((size_t)(b * 256 + wid * 16 + l15) << 12) + ltg * 128 + quad * 8;
    s16x8 bv2[4];
    #pragma unroll
    for (int kc = 0; kc < 4; ++kc)
        bv2[kc] = *reinterpret_cast<const s16x8*>(vrow + kc * 32);
    __syncthreads();
    // ---- Phase A: QK^T (16 rows x 32 n per wave) ----
    f32x4 sa[2];
    sa[0] = ZERO4; sa[1] = ZERO4;
    #pragma unroll
    for (int kc = 0; kc < 8; ++kc) {
        #pragma unroll
        for (int fn = 0; fn < 2; ++fn) {
            s16x8 bv = *reinterpret_cast<const s16x8*>(
                qls + (fnh * 32 + fn * 16 + l15) * 264 + kc * 32 + quad * 8);
            sa[fn] = mfma16(av[kc], bv, sa[fn]);
        }
    }
    // ---- softmax over n = 64: partial (32 n) in-wave, combine across fnh pair via LDS ----
    float mx[4];
    #pragma unroll
    for (int r = 0; r < 4; ++r) {
        float m = fmaxf(sa[0][r], sa[1][r]);
        #pragma unroll
        for (int msk = 1; msk <= 8; msk <<= 1) m = fmaxf(m, __shfl_xor(m, msk, 64));
        mx[r] = m;
    }
    if (l15 == 0) {
        #pragma unroll
        for (int r = 0; r < 4; ++r) smx[rowgrp][fnh][quad * 4 + r] = mx[r];
    }
    __syncthreads();
    float e[2][4], ps[4];
    #pragma unroll
    for (int r = 0; r < 4; ++r) {
        float g = fmaxf(mx[r], smx[rowgrp][1 - fnh][quad * 4 + r]);
        e[0][r] = __expf(sa[0][r] - g);
        e[1][r] = __expf(sa[1][r] - g);
        float s = e[0][r] + e[1][r];
        #pragma unroll
        for (int msk = 1; msk <= 8; msk <<= 1) s += __shfl_xor(s, msk, 64);
        ps[r] = s;
    }
    if (l15 == 0) {
        #pragma unroll
        for (int r = 0; r < 4; ++r) ssm[rowgrp][fnh][quad * 4 + r] = ps[r];
    }
    __syncthreads();
    float colp[2] = {0.f, 0.f};
    #pragma unroll
    for (int r = 0; r < 4; ++r) {
        float inv = 1.f / (ps[r] + ssm[rowgrp][1 - fnh][quad * 4 + r]);
        #pragma unroll
        for (int fn = 0; fn < 2; ++fn) {
            float p = e[fn][r] * inv + 1e-8f;
            colp[fn] += p;
            atile[(fnh * 32 + fn * 16 + l15) * 136 + rowgrp * 16 + quad * 4 + r] = f2bf(p);
        }
    }
    // ---- colsum partials: per-wave over its 16 rows, combine 8 rowgrps via LDS ----
    #pragma unroll
    for (int fn = 0; fn < 2; ++fn) {
        float c = colp[fn];
        c += __shfl_xor(c, 16, 64);
        c += __shfl_xor(c, 32, 64);
        if (lane < 16) colsh[fnh * 32 + fn * 16 + lane][rowgrp] = c;
    }
    __syncthreads();
    if (tid < 64) {
        float s = 0;
        #pragma unroll
        for (int rg = 0; rg < 8; ++rg) s += colsh[tid][rg];
        cs_part[((b << 5) + ltg) * 64 + tid] = s;
    }
    // ---- Phase B: PV (K = 128 l); wave -> 16-d slice; 16 atomics/thread ----
    {
        f32x4 pacc[4];
        #pragma unroll
        for (int i = 0; i < 4; ++i) pacc[i] = ZERO4;
        #pragma unroll
        for (int kc = 0; kc < 4; ++kc) {
            #pragma unroll
            for (int fm = 0; fm < 4; ++fm) {
                s16x8 a = *reinterpret_cast<const s16x8*>(
                    atile + (fm * 16 + l15) * 136 + kc * 32 + quad * 8);
                pacc[fm] = mfma16(a, bv2[kc], pacc[fm]);
            }
        }
        int d = wid * 16 + l15;
        #pragma unroll
        for (int fm = 0; fm < 4; ++fm)
            #pragma unroll
            for (int r = 0; r < 4; ++r) {
                int n = fm * 16 + quad * 4 + r;
                atomicAdd(&delta[(size_t)(b * 64 + n) * 256 + d], pacc[fm][r]);
            }
    }
    // ---- Phase C: P tile -> attnT on last iter only ----
    if (last) {
        int n = tid >> 4, lo = (tid & 15) * 8;
        const u16* src = atile + n * 136 + lo;
        u16* dst = attnT + (size_t)((b * 64 + n) << 12) + ltg * 128 + lo;
        *(int4*)(dst) = *(const int4*)(src);
    }
}

// ============ kT: tpl += delta/colsum (then zero delta); LN_m; MLP; LN_t + q; kE on last ====
// grid 32; b = blk&7 (XCD-pinned); 16 templates per block; 512 threads (8 waves)
__global__ __launch_bounds__(512) void kT(
    float* __restrict__ tpl, float* __restrict__ delta, const float* __restrict__ cs_part,
    const float* __restrict__ ln_m_g, const float* __restrict__ ln_m_b,
    const u16* __restrict__ W1T, const float* __restrict__ b1,
    const u16* __restrict__ W2T, const float* __restrict__ b2,
    const float* __restrict__ ln_t_g, const float* __restrict__ ln_t_b,
    const u16* __restrict__ WqP, u16* __restrict__ qbuf,
    int last, const u16* __restrict__ attnT, float* __restrict__ out0, float* __restrict__ out1)
{
    __shared__ __align__(16) u16 mls[16 * 264];      // 8448
    __shared__ __align__(16) u16 hid[16 * 520];      // 16640
    __shared__ float pls[16][32][2];                 // 4096
    __shared__ float stat[16][2];
    __shared__ float lnr2[8][16][2];                 // 1024
    __shared__ float csh[16];
    int b = blockIdx.x & 7, mg = blockIdx.x >> 3;    // XCD pin: b = blk%8
    int m0 = mg * 16;
    int tid = threadIdx.x, wid = tid >> 6, lane = tid & 63;
    int quad = lane >> 4, l15 = lane & 15;
    // ---- phase 0: reduce colsum partials ----
    if (tid < 16) {
        float s = 0;
        #pragma unroll
        for (int g = 0; g < 32; ++g) s += cs_part[((b << 5) + g) * 64 + m0 + tid];
        csh[tid] = 1.f / s;
    }
    __syncthreads();
    // ---- phase 1: v = tpl + delta/colsum; zero delta; LN_m -> mls; tpl = v ----
    {
        int ml = tid >> 5, part = tid & 31;
        float cinv = csh[ml];
        float* tg = tpl + (b * 64 + m0 + ml) * 256 + part * 8;
        float* dg = delta + (size_t)(b * 64 + m0 + ml) * 256 + part * 8;
        float vbuf[8];
        float s = 0, q2 = 0;
        #pragma unroll
        for (int i = 0; i < 8; ++i) {
            float v = tg[i] + dg[i] * cinv;
            vbuf[i] = v; s += v; q2 += v * v;
        }
        if (!last) {
            f32x4* dz = (f32x4*)dg;
            dz[0] = ZERO4; dz[1] = ZERO4;
        }
        pls[ml][part][0] = s; pls[ml][part][1] = q2;
        __syncthreads();
        if (tid < 16) {
            float ss = 0, qq = 0;
            #pragma unroll
            for (int p = 0; p < 32; ++p) { ss += pls[tid][p][0]; qq += pls[tid][p][1]; }
            float mu = ss * (1.f / 256.f);
            float var = fmaxf(qq * (1.f / 256.f) - mu * mu, 0.f);
            stat[tid][0] = mu; stat[tid][1] = rsqrtf(var + 1e-5f);
        }
        __syncthreads();
        float mu = stat[ml][0], rs = stat[ml][1];
        #pragma unroll
        for (int i = 0; i < 8; ++i) {
            int d = part * 8 + i;
            tg[i] = vbuf[i];
            mls[ml * 264 + d] = f2bf((vbuf[i] - mu) * rs * ln_m_g[d] + ln_m_b[d]);
        }
    }
    __syncthreads();
    // ---- G1: hid = gelu(mls @ W1 + b1); 8 waves, wave -> 64 nh ----
    {
        f32x4 ha[4];
        #pragma unroll
        for (int j = 0; j < 4; ++j) ha[j] = ZERO4;
        #pragma unroll 1
        for (int kc = 0; kc < 8; ++kc) {
            s16x8 a = *reinterpret_cast<const s16x8*>(mls + l15 * 264 + kc * 32 + quad * 8);
            #pragma unroll
            for (int fn = 0; fn < 4; ++fn) {
                s16x8 bv = *reinterpret_cast<const s16x8*>(W1T + (wid * 64 + fn * 16 + l15) * 256 + kc * 32 + quad * 8);
                ha[fn] = mfma16(a, bv, ha[fn]);
            }
        }
        #pragma unroll
        for (int fn = 0; fn < 4; ++fn) {
            int nh = wid * 64 + fn * 16 + l15;
            float bb = b1[nh];
            #pragma unroll
            for (int r = 0; r < 4; ++r) {
                float v = ha[fn][r] + bb;
                v = 0.5f * v * (1.f + erff(v * 0.70710678118654752f));
                hid[(quad * 4 + r) * 520 + nh] = f2bf(v);
            }
        }
    }
    __syncthreads();
    // ---- G2: new = tpl + hid @ W2 + b2; LN_t -> mls; out0 on last; wave -> 32 d ----
    {
        f32x4 oa[2];
        oa[0] = ZERO4; oa[1] = ZERO4;
        #pragma unroll 1
        for (int kc = 0; kc < 16; ++kc) {
            s16x8 a = *reinterpret_cast<const s16x8*>(hid + l15 * 520 + kc * 32 + quad * 8);
            #pragma unroll
            for (int fn = 0; fn < 2; ++fn) {
                s16x8 bv = *reinterpret_cast<const s16x8*>(W2T + (wid * 32 + fn * 16 + l15) * 512 + kc * 32 + quad * 8);
                oa[fn] = mfma16(a, bv, oa[fn]);
            }
        }
        #pragma unroll
        for (int fn = 0; fn < 2; ++fn) {
            int d = wid * 32 + fn * 16 + l15;
            float bb = b2[d];
            #pragma unroll
            for (int r = 0; r < 4; ++r) {
                int mm = quad * 4 + r;
                oa[fn][r] += bb + tpl[(b * 64 + m0 + mm) * 256 + d];
            }
        }
        #pragma unroll
        for (int r = 0; r < 4; ++r) {
            float s = oa[0][r] + oa[1][r];
            float q2 = oa[0][r] * oa[0][r] + oa[1][r] * oa[1][r];
            #pragma unroll
            for (int msk = 1; msk <= 8; msk <<= 1) {
                s  += __shfl_xor(s, msk, 64);
                q2 += __shfl_xor(q2, msk, 64);
            }
            if (l15 == 0) {
                lnr2[wid][quad * 4 + r][0] = s;
                lnr2[wid][quad * 4 + r][1] = q2;
            }
        }
        __syncthreads();
        if (tid < 16) {
            float ss = 0, qq = 0;
            #pragma unroll
            for (int w = 0; w < 8; ++w) { ss += lnr2[w][tid][0]; qq += lnr2[w][tid][1]; }
            float mu = ss * (1.f / 256.f);
            float var = fmaxf(qq * (1.f / 256.f) - mu * mu, 0.f);
            stat[tid][0] = mu; stat[tid][1] = rsqrtf(var + 1e-5f);
        }
        __syncthreads();
        #pragma unroll
        for (int fn = 0; fn < 2; ++fn) {
            int d = wid * 32 + fn * 16 + l15;
            float gg = last ? 0.f : ln_t_g[d];
            float bt = last ? 0.f : ln_t_b[d];
            #pragma unroll
            for (int r = 0; r < 4; ++r) {
                int mm = quad * 4 + r;
                float v = oa[fn][r];
                tpl[(b * 64 + m0 + mm) * 256 + d] = v;
                if (last) {
                    out0[(b * 256 + d) * 64 + m0 + mm] = v;
                } else {
                    mls[mm * 264 + d] = f2bf((v - stat[mm][0]) * stat[mm][1] * gg + bt);
                }
            }
        }
    }
    if (!last) {
        __syncthreads();
        // ---- q-GEMM for next iteration; wave -> 32 d ----
        f32x4 qa[2];
        qa[0] = ZERO4; qa[1] = ZERO4;
        #pragma unroll 1
        for (int kc = 0; kc < 8; ++kc) {
            s16x8 a = *reinterpret_cast<const s16x8*>(mls + l15 * 264 + kc * 32 + quad * 8);
            #pragma unroll
            for (int fn = 0; fn < 2; ++fn) {
                s16x8 bv = *reinterpret_cast<const s16x8*>(WqP + (wid * 32 + fn * 16 + l15) * 256 + kc * 32 + quad * 8);
                qa[fn] = mfma16(a, bv, qa[fn]);
            }
        }
        #pragma unroll
        for (int fn = 0; fn < 2; ++fn)
            #pragma unroll
            for (int r = 0; r < 4; ++r) {
                int mt = m0 + quad * 4 + r;
                int d = wid * 32 + fn * 16 + l15;
                qbuf[(b * 64 + mt) * 256 + d] = f2bf(qa[fn][r] * 0.0625f);
            }
    } else {
        // ---- kE folded: attn_out = attnT / colsum for this block's 16 n rows ----
        int n = m0 + (tid >> 5);
        int c0 = (tid & 31) * 128;
        float ci = csh[tid >> 5];
        const u16* src = attnT + ((size_t)(b * 64 + n) << 12) + c0;
        float* dst = out1 + ((size_t)(b * 64 + n) << 12) + c0;
        #pragma unroll 4
        for (int j = 0; j < 128; j += 4) {
            us4 w = *(const us4*)(src + j);
            f32x4 o;
            o.x = bf2f(w.x) * ci; o.y = bf2f(w.y) * ci;
            o.z = bf2f(w.z) * ci; o.w = bf2f(w.w) * ci;
            *(f32x4*)(dst + j) = o;
        }
    }
}

// ============ launch ============
extern "C" void kernel_launch(void* const* d_in, const int* in_sizes, int n_in,
                              void* d_out, int out_size, void* d_ws, size_t ws_size,
                              hipStream_t stream)
{
    const float* x       = (const float*)d_in[0];
    const float* tinit   = (const float*)d_in[1];
    const float* conv_w  = (const float*)d_in[2];
    const float* conv_b  = (const float*)d_in[3];
    const float* Wq      = (const float*)d_in[4];
    const float* Wk      = (const float*)d_in[5];
    const float* Wv      = (const float*)d_in[6];
    const float* ln_in_g = (const float*)d_in[7];
    const float* ln_in_b = (const float*)d_in[8];
    const float* ln_t_g  = (const float*)d_in[9];
    const float* ln_t_b  = (const float*)d_in[10];
    const float* ln_m_g  = (const float*)d_in[11];
    const float* ln_m_b  = (const float*)d_in[12];
    const float* W1      = (const float*)d_in[13];
    const float* b1      = (const float*)d_in[14];
    const float* W2      = (const float*)d_in[15];
    const float* b2      = (const float*)d_in[16];

    char* ws = (char*)d_ws;
    u16* Bp       = (u16*)(ws + 0);          // 2,359,296
    u16* WkvP     = (u16*)(ws + 2359296);    //   262,144
    u16* WqP      = (u16*)(ws + 2621440);    //   131,072
    u16* W1T      = (u16*)(ws + 2752512);    //   262,144
    u16* W2T      = (u16*)(ws + 3014656);    //   262,144
    u16* kbuf     = (u16*)(ws + 3276800);    // 16,777,216
    u16* vT       = (u16*)(ws + 20054016);   // 16,777,216
    u16* qbuf     = (u16*)(ws + 36831232);   //   262,144
    u16* attnT    = (u16*)(ws + 37093376);   // 4,194,304  (written last iter only)
    float* tpl    = (float*)(ws + 41289728); //   524,288
    float* delta  = (float*)(ws + 41814016); //   524,288
    float* cs_part= (float*)(ws + 42338304); //    65,536   (total ~42.4 MB)

    float* out0 = (float*)d_out;      // templates_out (8,256,64)
    float* out1 = out0 + 131072;      // attn_out (8,64,16,16,16)

    prepack_kernel<<<2944, 256, 0, stream>>>(conv_w, Wk, Wv, Wq, W1, W2, Bp, WkvP, WqP, W1T, W2T);
    conv_fused<<<512, 512, 0, stream>>>(x, Bp, conv_b, ln_in_g, ln_in_b, WkvP, kbuf, vT);
    kQ<<<8, 256, 0, stream>>>(tinit, tpl, ln_t_g, ln_t_b, WqP, qbuf, delta);
    for (int it = 0; it < 6; ++it) {
        int last = (it == 5) ? 1 : 0;
        kA<<<256, 1024, 0, stream>>>(qbuf, kbuf, vT, cs_part, delta, last, attnT);
        kT<<<32, 512, 0, stream>>>(tpl, delta, cs_part, ln_m_g, ln_m_b, W1T, b1,
                                   W2T, b2, ln_t_g, ln_t_b, WqP, qbuf, last, attnT, out0, out1);
    }
}